// Round 3
// baseline (1805.620 us; speedup 1.0000x reference)
//
#include <hip/hip_runtime.h>

#define NN   100000
#define EE   3200000
#define DIN  83
#define DHID 1024
#define NCLS 25
#define XPAD 96    // x/ax bf16 row padding (192 B = 3 cache lines)
#define ZPAD 32    // z bf16 row padding (64 B = 1 cache line)

#define NBK     391   // buckets of 256 rows (row >> 8)
#define CHUNK   8192  // edges per partition block

#define CB      13            // column-chunk shift: 8192 cols = 1.57 MB of x
#define NP      13            // ceil(100000 / 8192)
#define NKEY    (NP * 256)    // 3328 (chunk, rowlocal) keys per bucket
#define NWAVE   (NN / 16)     // 6250 persistent waves, 16 rows each

typedef __attribute__((__ext_vector_type__(8))) short sh8;
typedef __attribute__((__ext_vector_type__(4))) float f4_t;

static __device__ __forceinline__ float relu_(float v) { return v > 0.f ? v : 0.f; }

// f32 -> bf16 (RNE)
static __device__ __forceinline__ unsigned short f2bf(float f) {
  unsigned int u = __float_as_uint(f);
  unsigned int r = u + 0x7FFFu + ((u >> 16) & 1u);
  return (unsigned short)(r >> 16);
}
// packed bf16 pair -> two f32
static __device__ __forceinline__ float bflo(unsigned int q) {
  return __uint_as_float(q << 16);
}
static __device__ __forceinline__ float bfhi(unsigned int q) {
  return __uint_as_float(q & 0xFFFF0000u);
}

// K1: Conv1d(1->4,k5,p2) + channel-sum + bias + relu -> bf16 x[NN][96]
__global__ void conv_relu_k(const float* __restrict__ feature,
                            const float* __restrict__ conv_w,
                            const float* __restrict__ conv_b,
                            unsigned short* __restrict__ x) {
  float ws0 = conv_w[0] + conv_w[5] + conv_w[10] + conv_w[15];
  float ws1 = conv_w[1] + conv_w[6] + conv_w[11] + conv_w[16];
  float ws2 = conv_w[2] + conv_w[7] + conv_w[12] + conv_w[17];
  float ws3 = conv_w[3] + conv_w[8] + conv_w[13] + conv_w[18];
  float ws4 = conv_w[4] + conv_w[9] + conv_w[14] + conv_w[19];
  float bs  = conv_b[0] + conv_b[1] + conv_b[2] + conv_b[3];
  const int total = NN * XPAD;
  for (int idx = blockIdx.x * blockDim.x + threadIdx.x; idx < total;
       idx += gridDim.x * blockDim.x) {
    int n = idx / XPAD;
    int i = idx - n * XPAD;
    unsigned short o = 0;
    if (i < DIN) {
      const float* f = feature + (size_t)n * DIN;
      float acc = bs;
      if (i >= 2)      acc += ws0 * f[i - 2];
      if (i >= 1)      acc += ws1 * f[i - 1];
      acc += ws2 * f[i];
      if (i + 1 < DIN) acc += ws3 * f[i + 1];
      if (i + 2 < DIN) acc += ws4 * f[i + 2];
      o = f2bf(relu_(acc));
    }
    x[idx] = o;
  }
}

// Combined prep: w1t transpose, w2t transpose, gbk zero
__global__ void prep_k(const float* __restrict__ W1, unsigned short* __restrict__ w1t,
                       const float* __restrict__ W2, unsigned short* __restrict__ w2t,
                       int* __restrict__ gbk) {
  int idx = blockIdx.x * blockDim.x + threadIdx.x;
  if (idx < DHID * XPAD) {            // w1t[1024][96], K zero-padded
    int k = idx / DHID;
    int n = idx - k * DHID;
    float v = (k < DIN) ? W1[k * DHID + n] : 0.f;
    w1t[n * XPAD + k] = f2bf(v);
  }
  if (idx < 32 * DHID) {              // w2t[32][1024], N zero-padded
    int k = idx / 32;
    int n = idx - k * 32;
    float v = (n < NCLS) ? W2[k * NCLS + n] : 0.f;
    w2t[n * DHID + k] = f2bf(v);
  }
  if (idx < NBK * 16) gbk[idx] = 0;
}

// ---- CSR build (bucket-hierarchical) ----

__global__ __launch_bounds__(512) void bucket_hist_k(
    const int* __restrict__ row, int* __restrict__ gbk) {
  __shared__ int cnt[NBK];
  const int tid = threadIdx.x;
  for (int b = tid; b < NBK; b += 512) cnt[b] = 0;
  __syncthreads();
  const int cb = blockIdx.x * CHUNK;
  const int csize = (cb + CHUNK <= EE) ? CHUNK : (EE - cb);
  for (int i = tid; i < csize; i += 512)
    atomicAdd(&cnt[row[cb + i] >> 8], 1);
  __syncthreads();
  for (int b = tid; b < NBK; b += 512)
    if (cnt[b]) atomicAdd(&gbk[b * 16], cnt[b]);
}

__global__ void scan_buckets_k(const int* __restrict__ gbk,
                               int* __restrict__ bbase, int* __restrict__ gcur) {
  __shared__ int sd[512];
  int t = threadIdx.x;
  int v = (t < NBK) ? gbk[t * 16] : 0;
  sd[t] = v;
  __syncthreads();
  for (int off = 1; off < 512; off <<= 1) {
    int add = (t >= off) ? sd[t - off] : 0;
    __syncthreads();
    sd[t] += add;
    __syncthreads();
  }
  if (t < NBK) {
    int excl = sd[t] - v;
    bbase[t] = excl;
    gcur[t * 16] = excl;   // line-padded cursor
  }
  if (t == 0) bbase[NBK] = EE;
}

// Pass 1: partition into bucket-major tmp via direct reserved-range scatter.
__global__ __launch_bounds__(256) void partition_k(
    const float* __restrict__ vals, const int* __restrict__ row,
    const int* __restrict__ col, int* __restrict__ gcur,
    int2* __restrict__ tmp) {
  __shared__ int cnt[NBK];
  __shared__ int lcur[NBK];
  const int tid = threadIdx.x;
  const int cb = blockIdx.x * CHUNK;
  const int csize = (cb + CHUNK <= EE) ? CHUNK : (EE - cb);

  for (int b = tid; b < NBK; b += 256) cnt[b] = 0;
  __syncthreads();
  for (int i = tid; i < csize; i += 256)
    atomicAdd(&cnt[row[cb + i] >> 8], 1);
  __syncthreads();
  for (int b = tid; b < NBK; b += 256)
    lcur[b] = cnt[b] ? atomicAdd(&gcur[b * 16], cnt[b]) : 0;
  __syncthreads();
  for (int i = tid; i < csize; i += 256) {
    int r = row[cb + i];
    int pos = atomicAdd(&lcur[r >> 8], 1);
    tmp[pos] = make_int2(col[cb + i] | ((r & 255) << 17),
                         __float_as_int(vals[cb + i]));
  }
}

// Pass 2: per-bucket (chunk, row)-key counting sort (LDS hist over 3328 keys).
// Output csr2 is globally (bucket, chunk, rowlocal)-sorted; off3[b][p][rloc]
// gives every cell boundary (monotone flat array, sentinel = EE).
__global__ __launch_bounds__(512) void fine_scatter3_k(
    const int* __restrict__ bbase, const int2* __restrict__ tmp,
    int2* __restrict__ csr2, int* __restrict__ off3) {
  __shared__ int cnt[3584];    // NKEY=3328 padded to 512*7
  __shared__ int lcur[3584];
  __shared__ int sd[512];
  const int tid = threadIdx.x;
  const int b = blockIdx.x;
  const int gstart = bbase[b];
  const int nedge = bbase[b + 1] - gstart;
  for (int k = tid; k < 3584; k += 512) cnt[k] = 0;
  __syncthreads();
  // Phase A: (chunk, rowlocal) histogram
  for (int i = tid; i < nedge; i += 512) {
    int px = tmp[gstart + i].x;
    int key = ((px & 0x1FFFF) >> CB) * 256 + (int)(((unsigned)px) >> 17);
    atomicAdd(&cnt[key], 1);
  }
  __syncthreads();
  // Phase B: exclusive scan of 3584 = 512 threads x 7 serial
  int v[7];
  int run = 0;
#pragma unroll
  for (int j = 0; j < 7; ++j) { v[j] = cnt[tid * 7 + j]; run += v[j]; }
  sd[tid] = run;
  __syncthreads();
  for (int off = 1; off < 512; off <<= 1) {
    int add = (tid >= off) ? sd[tid - off] : 0;
    __syncthreads();
    sd[tid] += add;
    __syncthreads();
  }
  int base = gstart + sd[tid] - run;
#pragma unroll
  for (int j = 0; j < 7; ++j) { cnt[tid * 7 + j] = base; base += v[j]; }
  __syncthreads();
  for (int k = tid; k < 3584; k += 512) lcur[k] = cnt[k];
  for (int k = tid; k < NKEY; k += 512) off3[b * NKEY + k] = cnt[k];
  if (b == NBK - 1 && tid == 0) off3[NBK * NKEY] = EE;
  __syncthreads();
  // Phase C: scatter within the bucket's ~64KB window (L2-local)
  for (int i = tid; i < nedge; i += 512) {
    int2 p = tmp[gstart + i];
    int rloc = (int)(((unsigned)p.x) >> 17);
    int key = ((p.x & 0x1FFFF) >> CB) * 256 + rloc;
    int pos = atomicAdd(&lcur[key], 1);
    csr2[pos] = make_int2((p.x & 0x1FFFF) | ((rloc & 15) << 17), p.y);
  }
}

// flush running pair into the named accumulator (scur is wave-uniform scalar)
#define FLUSH16(SCUR, C0, C1)                              \
  switch (SCUR) {                                          \
    case 0:  a0[0]  += (C0); a1[0]  += (C1); break;        \
    case 1:  a0[1]  += (C0); a1[1]  += (C1); break;        \
    case 2:  a0[2]  += (C0); a1[2]  += (C1); break;        \
    case 3:  a0[3]  += (C0); a1[3]  += (C1); break;        \
    case 4:  a0[4]  += (C0); a1[4]  += (C1); break;        \
    case 5:  a0[5]  += (C0); a1[5]  += (C1); break;        \
    case 6:  a0[6]  += (C0); a1[6]  += (C1); break;        \
    case 7:  a0[7]  += (C0); a1[7]  += (C1); break;        \
    case 8:  a0[8]  += (C0); a1[8]  += (C1); break;        \
    case 9:  a0[9]  += (C0); a1[9]  += (C1); break;        \
    case 10: a0[10] += (C0); a1[10] += (C1); break;        \
    case 11: a0[11] += (C0); a1[11] += (C1); break;        \
    case 12: a0[12] += (C0); a1[12] += (C1); break;        \
    case 13: a0[13] += (C0); a1[13] += (C1); break;        \
    case 14: a0[14] += (C0); a1[14] += (C1); break;        \
    case 15: a0[15] += (C0); a1[15] += (C1); break;        \
    default: break;                                        \
  }

// ---- persistent chunk-phased gather SpMM, D=83(96 bf16) ----
// 6250 waves; wave w owns rows [16w,16w+16), 32 f32 accs in registers.
// 13 column-chunk phases; all resident waves sweep the same 1.57 MB x-chunk
// -> per-XCD L2 captures the reuse structurally. Run-boundary switch-flush,
// zero per-edge atomics.
__global__ __launch_bounds__(512, 8) void spmm83_p(
    const int* __restrict__ off3, const int2* __restrict__ csr2,
    const unsigned short* __restrict__ x, unsigned short* __restrict__ ax) {
  const int gw = (int)((blockIdx.x * 512 + threadIdx.x) >> 6);
  const int lane = threadIdx.x & 63;
  if (gw >= NWAVE) return;
  const int b = gw >> 4;
  const int g0 = (gw & 15) << 4;
  const bool act = lane < 48;          // 48 lanes x bf16-pair = 96 dims
  const int d2 = lane * 2;
  float a0[16], a1[16];
#pragma unroll
  for (int k = 0; k < 16; ++k) { a0[k] = 0.f; a1[k] = 0.f; }

  for (int p = 0; p < NP; ++p) {
    const int kb = b * NKEY + p * 256 + g0;
    const int s = __builtin_amdgcn_readfirstlane(off3[kb]);
    const int e = __builtin_amdgcn_readfirstlane(off3[kb + 16]);
    int scur = 0;
    float c0 = 0.f, c1 = 0.f;
    int i = s;
    for (; i + 4 <= e; i += 4) {
      int2 p4[4];
#pragma unroll
      for (int u = 0; u < 4; ++u) p4[u] = csr2[i + u];
      unsigned q[4];
      if (act) {
#pragma unroll
        for (int u = 0; u < 4; ++u)
          q[u] = *(const unsigned*)&x[(size_t)(p4[u].x & 0x1FFFF) * XPAD + d2];
      }
#pragma unroll
      for (int u = 0; u < 4; ++u) {
        int srl = __builtin_amdgcn_readfirstlane((int)(((unsigned)p4[u].x) >> 17));
        if (srl != scur) {
          FLUSH16(scur, c0, c1);
          scur = srl; c0 = 0.f; c1 = 0.f;
        }
        float v = __int_as_float(p4[u].y);
        c0 += v * bflo(q[u]);
        c1 += v * bfhi(q[u]);
      }
    }
    for (; i < e; ++i) {
      int2 pe = csr2[i];
      unsigned q = 0;
      if (act) q = *(const unsigned*)&x[(size_t)(pe.x & 0x1FFFF) * XPAD + d2];
      int srl = __builtin_amdgcn_readfirstlane((int)(((unsigned)pe.x) >> 17));
      if (srl != scur) {
        FLUSH16(scur, c0, c1);
        scur = srl; c0 = 0.f; c1 = 0.f;
      }
      float v = __int_as_float(pe.y);
      c0 += v * bflo(q);
      c1 += v * bfhi(q);
    }
    FLUSH16(scur, c0, c1);
  }

  if (act) {
    const int r0 = gw << 4;
#pragma unroll
    for (int k = 0; k < 16; ++k) {
      unsigned o = (unsigned)f2bf(a0[k]) | ((unsigned)f2bf(a1[k]) << 16);
      *(unsigned*)&ax[(size_t)(r0 + k) * XPAD + d2] = o;
    }
  }
}

// ---- persistent chunk-phased gather SpMM, D=25(32 bf16), +b2 ----
// Same ownership (16 rows/wave). Whole wave processes one edge at a time:
// 4 lane-groups = 4 candidate rows; cndmask row-match; one 64B zb line/edge.
__global__ __launch_bounds__(512, 8) void spmm25_p(
    const int* __restrict__ off3, const int2* __restrict__ csr2,
    const unsigned short* __restrict__ zbt, const float* __restrict__ b2,
    float* __restrict__ out) {
  const int gw = (int)((blockIdx.x * 512 + threadIdx.x) >> 6);
  const int lane = threadIdx.x & 63;
  if (gw >= NWAVE) return;
  const int b = gw >> 4;
  const int g0 = (gw & 15) << 4;
  const int grp = lane >> 4;           // 0..3: which row of the 4-row run
  const int d2 = (lane & 15) * 2;      // 16 lanes x bf16-pair = 32 dims
  float acc0[4], acc1[4];
#pragma unroll
  for (int s = 0; s < 4; ++s) { acc0[s] = 0.f; acc1[s] = 0.f; }

  for (int p = 0; p < NP; ++p) {
    const int kb = b * NKEY + p * 256 + g0;
#pragma unroll
    for (int s = 0; s < 4; ++s) {
      const int st = __builtin_amdgcn_readfirstlane(off3[kb + s * 4]);
      const int en = __builtin_amdgcn_readfirstlane(off3[kb + s * 4 + 4]);
      const int myrl = s * 4 + grp;
      float t0 = acc0[s], t1 = acc1[s];
      int i = st;
      for (; i + 4 <= en; i += 4) {
        int2 p4[4];
#pragma unroll
        for (int u = 0; u < 4; ++u) p4[u] = csr2[i + u];
#pragma unroll
        for (int u = 0; u < 4; ++u) {
          unsigned q = *(const unsigned*)&zbt[(size_t)(p4[u].x & 0x1FFFF) * ZPAD + d2];
          int rl = (int)(((unsigned)p4[u].x) >> 17);
          float v = (rl == myrl) ? __int_as_float(p4[u].y) : 0.f;
          t0 += v * bflo(q);
          t1 += v * bfhi(q);
        }
      }
      for (; i < en; ++i) {
        int2 pe = csr2[i];
        unsigned q = *(const unsigned*)&zbt[(size_t)(pe.x & 0x1FFFF) * ZPAD + d2];
        int rl = (int)(((unsigned)pe.x) >> 17);
        float v = (rl == myrl) ? __int_as_float(pe.y) : 0.f;
        t0 += v * bflo(q);
        t1 += v * bfhi(q);
      }
      acc0[s] = t0; acc1[s] = t1;
    }
  }

  const int r0 = gw << 4;
#pragma unroll
  for (int s = 0; s < 4; ++s) {
    int r = r0 + s * 4 + grp;
    if (d2 < NCLS)     out[(size_t)r * NCLS + d2]     = acc0[s] + b2[d2];
    if (d2 + 1 < NCLS) out[(size_t)r * NCLS + d2 + 1] = acc1[s] + b2[d2 + 1];
  }
}

// ---- Fused MLP via bf16 MFMA: z = relu(ax@W1+b1)@W2, z -> bf16[NN][32] ----
// Block = 128 nodes, 4 waves, hidden chunked x128 (8 chunks).
__global__ __launch_bounds__(256) void fused_mlp_mfma(
    const unsigned short* __restrict__ axg, const unsigned short* __restrict__ w1t,
    const float* __restrict__ b1, const unsigned short* __restrict__ w2t,
    unsigned short* __restrict__ zb) {
  __shared__ __align__(16) unsigned short axs[128 * 104];  // 26.6 KB
  __shared__ __align__(16) unsigned short hs[128 * 136];   // 34.8 KB (chunk 128)
  __shared__ float b1s[DHID];                              // 4 KB
  const int tid = threadIdx.x;
  const int n0 = blockIdx.x * 128;

  for (int idx = tid; idx < 128 * 12; idx += 256) {   // 12 sh8 chunks per row
    int m = idx / 12;
    int c8 = idx - m * 12;
    int node = n0 + m;
    sh8 v = {0, 0, 0, 0, 0, 0, 0, 0};
    if (node < NN) v = *(const sh8*)&axg[(size_t)node * XPAD + c8 * 8];
    *(sh8*)&axs[m * 104 + c8 * 8] = v;
  }
  for (int i = tid; i < DHID; i += 256) b1s[i] = b1[i];
  __syncthreads();

  const int lane = tid & 63;
  const int w = tid >> 6;
  const int quad = lane >> 4;   // A/B frag: k = quad*8 + j
  const int tn = lane & 15;     // A frag: m; B frag: n; C frag: col
  const int mta = w;            // GEMM2 m-tile 1
  const int mtb = w + 4;        // GEMM2 m-tile 2

  sh8 a1[8][3];
#pragma unroll
  for (int mt = 0; mt < 8; ++mt)
#pragma unroll
    for (int kc = 0; kc < 3; ++kc)
      a1[mt][kc] = *(const sh8*)&axs[(mt * 16 + tn) * 104 + kc * 32 + quad * 8];

  f4_t za0 = {0.f, 0.f, 0.f, 0.f}, za1 = {0.f, 0.f, 0.f, 0.f};
  f4_t zb0 = {0.f, 0.f, 0.f, 0.f}, zb1 = {0.f, 0.f, 0.f, 0.f};

  for (int c = 0; c < 8; ++c) {
    const int cb = c * 128;
    // GEMM1: wave w -> n-tiles w*2, w*2+1 ; all 8 m-tiles
#pragma unroll
    for (int nti = 0; nti < 2; ++nti) {
      const int nt = w * 2 + nti;
      const int ng = cb + nt * 16 + tn;
      const unsigned short* wr = &w1t[(size_t)ng * XPAD + quad * 8];
      sh8 b0 = *(const sh8*)&wr[0];
      sh8 b1f = *(const sh8*)&wr[32];
      sh8 b2f = *(const sh8*)&wr[64];
      float bias = b1s[ng];
#pragma unroll
      for (int mt = 0; mt < 8; ++mt) {
        f4_t acc = {0.f, 0.f, 0.f, 0.f};
        acc = __builtin_amdgcn_mfma_f32_16x16x32_bf16(a1[mt][0], b0, acc, 0, 0, 0);
        acc = __builtin_amdgcn_mfma_f32_16x16x32_bf16(a1[mt][1], b1f, acc, 0, 0, 0);
        acc = __builtin_amdgcn_mfma_f32_16x16x32_bf16(a1[mt][2], b2f, acc, 0, 0, 0);
#pragma unroll
        for (int r = 0; r < 4; ++r) {
          float v = relu_(acc[r] + bias);          // C: col=tn, row=quad*4+r
          hs[(mt * 16 + quad * 4 + r) * 136 + nt * 16 + tn] = f2bf(v);
        }
      }
    }
    __syncthreads();
    // GEMM2: z += h_chunk @ W2[cb..cb+127,:]; wave -> m-tiles w, w+4
#pragma unroll
    for (int kc = 0; kc < 4; ++kc) {
      sh8 bl = *(const sh8*)&w2t[(size_t)tn * DHID + cb + kc * 32 + quad * 8];
      sh8 bh = *(const sh8*)&w2t[(size_t)(16 + tn) * DHID + cb + kc * 32 + quad * 8];
      sh8 aa = *(const sh8*)&hs[(mta * 16 + tn) * 136 + kc * 32 + quad * 8];
      za0 = __builtin_amdgcn_mfma_f32_16x16x32_bf16(aa, bl, za0, 0, 0, 0);
      za1 = __builtin_amdgcn_mfma_f32_16x16x32_bf16(aa, bh, za1, 0, 0, 0);
      sh8 ab = *(const sh8*)&hs[(mtb * 16 + tn) * 136 + kc * 32 + quad * 8];
      zb0 = __builtin_amdgcn_mfma_f32_16x16x32_bf16(ab, bl, zb0, 0, 0, 0);
      zb1 = __builtin_amdgcn_mfma_f32_16x16x32_bf16(ab, bh, zb1, 0, 0, 0);
    }
    __syncthreads();
  }

#pragma unroll
  for (int r = 0; r < 4; ++r) {
    int na = n0 + mta * 16 + quad * 4 + r;
    if (na < NN) {
      zb[(size_t)na * ZPAD + tn]      = f2bf(za0[r]);
      zb[(size_t)na * ZPAD + 16 + tn] = f2bf(za1[r]);
    }
    int nb = n0 + mtb * 16 + quad * 4 + r;
    if (nb < NN) {
      zb[(size_t)nb * ZPAD + tn]      = f2bf(zb0[r]);
      zb[(size_t)nb * ZPAD + 16 + tn] = f2bf(zb1[r]);
    }
  }
}

extern "C" void kernel_launch(void* const* d_in, const int* in_sizes, int n_in,
                              void* d_out, int out_size, void* d_ws, size_t ws_size,
                              hipStream_t stream) {
  const float* feature = (const float*)d_in[0];
  const float* conv_w  = (const float*)d_in[1];
  const float* conv_b  = (const float*)d_in[2];
  const float* W1      = (const float*)d_in[3];
  const float* b1      = (const float*)d_in[4];
  const float* W2      = (const float*)d_in[5];
  const float* b2      = (const float*)d_in[6];
  const float* adj     = (const float*)d_in[7];
  const int*   erow    = (const int*)d_in[8];
  const int*   ecol    = (const int*)d_in[9];
  float* out = (float*)d_out;

  char* B = (char*)d_ws;
  size_t o = 0;
  auto alloc = [&](size_t bytes, size_t align) -> void* {
    o = (o + align - 1) & ~(align - 1);
    void* p = B + o;
    o += bytes;
    return p;
  };
  unsigned short* x    = (unsigned short*)alloc((size_t)NN * XPAD * 2, 16);
  unsigned short* ax   = (unsigned short*)alloc((size_t)NN * XPAD * 2, 16);
  unsigned short* zb   = (unsigned short*)alloc((size_t)NN * ZPAD * 2, 16);
  int*   gcur    = (int*)alloc((size_t)NBK * 16 * 4, 64);  // line-padded cursors
  int*   gbk     = (int*)alloc((size_t)NBK * 16 * 4, 64);  // line-padded totals
  int*   bbase   = (int*)alloc((size_t)(NBK + 1) * 4, 16); // bucket bases
  int*   off3    = (int*)alloc(((size_t)NBK * NKEY + 1) * 4, 16); // 5.2 MB
  unsigned short* w1t = (unsigned short*)alloc((size_t)DHID * XPAD * 2, 16);
  unsigned short* w2t = (unsigned short*)alloc((size_t)32 * DHID * 2, 16);
  int2*  tmp     = (int2*)alloc((size_t)EE * 8, 16);  // bucket-major
  int2*  csr2    = (int2*)alloc((size_t)EE * 8, 16);  // (bucket,chunk,row)-sorted

  // 1) x = relu(conv_sum(feature)); weight transposes + gbk zero (merged)
  conv_relu_k<<<8192, 256, 0, stream>>>(feature, conv_w, conv_b, x);
  prep_k<<<(DHID * XPAD + 255) / 256, 256, 0, stream>>>(W1, w1t, W2, w2t, gbk);
  // 2) edge build: bucket hist -> scan -> partition -> (chunk,row) counting sort
  bucket_hist_k<<<(EE + CHUNK - 1) / CHUNK, 512, 0, stream>>>(erow, gbk);
  scan_buckets_k<<<1, 512, 0, stream>>>(gbk, bbase, gcur);
  partition_k<<<(EE + CHUNK - 1) / CHUNK, 256, 0, stream>>>(adj, erow, ecol, gcur, tmp);
  fine_scatter3_k<<<NBK, 512, 0, stream>>>(bbase, tmp, csr2, off3);
  // 3) ax = A @ x : persistent waves, 13 column-chunk phases, register accs
  spmm83_p<<<(NWAVE * 64 + 511) / 512, 512, 0, stream>>>(off3, csr2, x, ax);
  // 4) z = relu(ax @ W1 + b1) @ W2 via bf16 MFMA (128-node tiles) -> bf16 [NN][32]
  fused_mlp_mfma<<<(NN + 127) / 128, 256, 0, stream>>>(ax, w1t, b1, w2t, zb);
  // 5) out = A @ z + b2 : persistent waves, same phase structure
  spmm25_p<<<(NWAVE * 64 + 511) / 512, 512, 0, stream>>>(off3, csr2, zb, b2, out);
}

// Round 4
// 635.716 us; speedup vs baseline: 2.8403x; 2.8403x over previous
//
#include <hip/hip_runtime.h>

#define NN   100000
#define EE   3200000
#define DIN  83
#define DHID 1024
#define NCLS 25
#define XPAD 96    // x/ax bf16 row padding (192 B = 3 cache lines)
#define ZPAD 32    // z bf16 row padding (64 B = 1 cache line)

#define NBK     782   // buckets of 128 rows (row >> 7)
#define CHUNK   8192  // edges per partition block

#define CB      13            // column-chunk shift: 8192 cols = 1.57 MB of x
#define NP      13            // ceil(100000 / 8192) phases
#define NKEY    (NP * 128)    // 1664 (chunk, rowlocal) keys per bucket
#define PADK    2048          // NKEY padded to 512*4

typedef __attribute__((__ext_vector_type__(8))) short sh8;
typedef __attribute__((__ext_vector_type__(4))) float f4_t;

static __device__ __forceinline__ float relu_(float v) { return v > 0.f ? v : 0.f; }

// f32 -> bf16 (RNE)
static __device__ __forceinline__ unsigned short f2bf(float f) {
  unsigned int u = __float_as_uint(f);
  unsigned int r = u + 0x7FFFu + ((u >> 16) & 1u);
  return (unsigned short)(r >> 16);
}
// packed bf16 pair -> two f32
static __device__ __forceinline__ float bflo(unsigned int q) {
  return __uint_as_float(q << 16);
}
static __device__ __forceinline__ float bfhi(unsigned int q) {
  return __uint_as_float(q & 0xFFFF0000u);
}

// K1: Conv1d(1->4,k5,p2) + channel-sum + bias + relu -> bf16 x[NN][96]
__global__ void conv_relu_k(const float* __restrict__ feature,
                            const float* __restrict__ conv_w,
                            const float* __restrict__ conv_b,
                            unsigned short* __restrict__ x) {
  float ws0 = conv_w[0] + conv_w[5] + conv_w[10] + conv_w[15];
  float ws1 = conv_w[1] + conv_w[6] + conv_w[11] + conv_w[16];
  float ws2 = conv_w[2] + conv_w[7] + conv_w[12] + conv_w[17];
  float ws3 = conv_w[3] + conv_w[8] + conv_w[13] + conv_w[18];
  float ws4 = conv_w[4] + conv_w[9] + conv_w[14] + conv_w[19];
  float bs  = conv_b[0] + conv_b[1] + conv_b[2] + conv_b[3];
  const int total = NN * XPAD;
  for (int idx = blockIdx.x * blockDim.x + threadIdx.x; idx < total;
       idx += gridDim.x * blockDim.x) {
    int n = idx / XPAD;
    int i = idx - n * XPAD;
    unsigned short o = 0;
    if (i < DIN) {
      const float* f = feature + (size_t)n * DIN;
      float acc = bs;
      if (i >= 2)      acc += ws0 * f[i - 2];
      if (i >= 1)      acc += ws1 * f[i - 1];
      acc += ws2 * f[i];
      if (i + 1 < DIN) acc += ws3 * f[i + 1];
      if (i + 2 < DIN) acc += ws4 * f[i + 2];
      o = f2bf(relu_(acc));
    }
    x[idx] = o;
  }
}

// Combined prep: w1t transpose, w2t transpose, gbk zero
__global__ void prep_k(const float* __restrict__ W1, unsigned short* __restrict__ w1t,
                       const float* __restrict__ W2, unsigned short* __restrict__ w2t,
                       int* __restrict__ gbk) {
  int idx = blockIdx.x * blockDim.x + threadIdx.x;
  if (idx < DHID * XPAD) {            // w1t[1024][96], K zero-padded
    int k = idx / DHID;
    int n = idx - k * DHID;
    float v = (k < DIN) ? W1[k * DHID + n] : 0.f;
    w1t[n * XPAD + k] = f2bf(v);
  }
  if (idx < 32 * DHID) {              // w2t[32][1024], N zero-padded
    int k = idx / 32;
    int n = idx - k * 32;
    float v = (n < NCLS) ? W2[k * NCLS + n] : 0.f;
    w2t[n * DHID + k] = f2bf(v);
  }
  if (idx < NBK * 16) gbk[idx] = 0;
}

// ---- CSR build (bucket-hierarchical, 128-row buckets) ----

__global__ __launch_bounds__(512) void bucket_hist_k(
    const int* __restrict__ row, int* __restrict__ gbk) {
  __shared__ int cnt[NBK];
  const int tid = threadIdx.x;
  for (int b = tid; b < NBK; b += 512) cnt[b] = 0;
  __syncthreads();
  const int cb = blockIdx.x * CHUNK;
  const int csize = (cb + CHUNK <= EE) ? CHUNK : (EE - cb);
  for (int i = tid; i < csize; i += 512)
    atomicAdd(&cnt[row[cb + i] >> 7], 1);
  __syncthreads();
  for (int b = tid; b < NBK; b += 512)
    if (cnt[b]) atomicAdd(&gbk[b * 16], cnt[b]);
}

__global__ void scan_buckets_k(const int* __restrict__ gbk,
                               int* __restrict__ bbase, int* __restrict__ gcur) {
  __shared__ int sd[1024];
  int t = threadIdx.x;          // 1024 threads
  int v = (t < NBK) ? gbk[t * 16] : 0;
  sd[t] = v;
  __syncthreads();
  for (int off = 1; off < 1024; off <<= 1) {
    int add = (t >= off) ? sd[t - off] : 0;
    __syncthreads();
    sd[t] += add;
    __syncthreads();
  }
  if (t < NBK) {
    int excl = sd[t] - v;
    bbase[t] = excl;
    gcur[t * 16] = excl;   // line-padded cursor
  }
  if (t == 0) bbase[NBK] = EE;
}

// Pass 1: partition into bucket-major tmp via direct reserved-range scatter.
__global__ __launch_bounds__(256) void partition_k(
    const float* __restrict__ vals, const int* __restrict__ row,
    const int* __restrict__ col, int* __restrict__ gcur,
    int2* __restrict__ tmp) {
  __shared__ int cnt[NBK];
  __shared__ int lcur[NBK];
  const int tid = threadIdx.x;
  const int cb = blockIdx.x * CHUNK;
  const int csize = (cb + CHUNK <= EE) ? CHUNK : (EE - cb);

  for (int b = tid; b < NBK; b += 256) cnt[b] = 0;
  __syncthreads();
  for (int i = tid; i < csize; i += 256)
    atomicAdd(&cnt[row[cb + i] >> 7], 1);
  __syncthreads();
  for (int b = tid; b < NBK; b += 256)
    lcur[b] = cnt[b] ? atomicAdd(&gcur[b * 16], cnt[b]) : 0;
  __syncthreads();
  for (int i = tid; i < csize; i += 256) {
    int r = row[cb + i];
    int pos = atomicAdd(&lcur[r >> 7], 1);
    tmp[pos] = make_int2(col[cb + i] | ((r & 127) << 17),
                         __float_as_int(vals[cb + i]));
  }
}

// Pass 2: per-bucket (chunk, rowlocal) counting sort; validated in round 3.
// csr2 is globally (bucket, chunk, rowlocal)-sorted; off3 flat monotone
// boundary table with sentinel EE at index NBK*NKEY.
__global__ __launch_bounds__(512) void fine_scatter4_k(
    const int* __restrict__ bbase, const int2* __restrict__ tmp,
    int2* __restrict__ csr2, int* __restrict__ off3) {
  __shared__ int cnt[PADK];    // NKEY=1664 padded to 512*4
  __shared__ int lcur[PADK];
  __shared__ int sd[512];
  const int tid = threadIdx.x;
  const int b = blockIdx.x;
  const int gstart = bbase[b];
  const int nedge = bbase[b + 1] - gstart;
  for (int k = tid; k < PADK; k += 512) cnt[k] = 0;
  __syncthreads();
  // Phase A: (chunk, rowlocal) histogram
  for (int i = tid; i < nedge; i += 512) {
    int px = tmp[gstart + i].x;
    int key = ((px & 0x1FFFF) >> CB) * 128 + (int)(((unsigned)px) >> 17);
    atomicAdd(&cnt[key], 1);
  }
  __syncthreads();
  // Phase B: exclusive scan of 2048 = 512 threads x 4 serial
  int v[4];
  int run = 0;
#pragma unroll
  for (int j = 0; j < 4; ++j) { v[j] = cnt[tid * 4 + j]; run += v[j]; }
  sd[tid] = run;
  __syncthreads();
  for (int off = 1; off < 512; off <<= 1) {
    int add = (tid >= off) ? sd[tid - off] : 0;
    __syncthreads();
    sd[tid] += add;
    __syncthreads();
  }
  int base = gstart + sd[tid] - run;
#pragma unroll
  for (int j = 0; j < 4; ++j) { cnt[tid * 4 + j] = base; base += v[j]; }
  __syncthreads();
  for (int k = tid; k < PADK; k += 512) lcur[k] = cnt[k];
  for (int k = tid; k < NKEY; k += 512) off3[b * NKEY + k] = cnt[k];
  if (b == NBK - 1 && tid == 0) off3[NBK * NKEY] = EE;
  __syncthreads();
  // Phase C: scatter within the bucket's ~32KB window (L2-local)
  for (int i = tid; i < nedge; i += 512) {
    int2 p = tmp[gstart + i];
    int key = ((p.x & 0x1FFFF) >> CB) * 128 + (int)(((unsigned)p.x) >> 17);
    int pos = atomicAdd(&lcur[key], 1);
    csr2[pos] = p;   // keep col | (rloc<<17), val
  }
}

// ---- phased gather SpMM, D=83(96 bf16): one block per 128-row bucket ----
// LDS f32 accumulator [128][96]; wave w owns rows [16w,16w+16) exclusively.
// 13 column-chunk phases; all ~768 resident blocks sweep the same 1.57 MB
// x-chunk -> per-XCD L2 captures reuse. Run-boundary LDS float2 RMW only
// (no atomics, no register arrays -> no scratch).
__global__ __launch_bounds__(512) void spmm83_lds(
    const int* __restrict__ off3, const int2* __restrict__ csr2,
    const unsigned short* __restrict__ x, unsigned short* __restrict__ ax) {
  __shared__ float acc[128 * 96];   // 48 KB
  const int tid = threadIdx.x;
  const int b = blockIdx.x;
  for (int i = tid; i < 128 * 96; i += 512) acc[i] = 0.f;
  __syncthreads();
  const int w = tid >> 6;
  const int lane = tid & 63;
  const bool act = lane < 48;          // 48 lanes x bf16-pair = 96 dims
  const int d2 = lane * 2;

#define FLUSHL()                                             \
  do {                                                       \
    if (act) {                                               \
      float2* ap = (float2*)&acc[scur * 96 + d2];            \
      float2 t = *ap;                                        \
      t.x += c0; t.y += c1;                                  \
      *ap = t;                                               \
    }                                                        \
  } while (0)

  for (int p = 0; p < NP; ++p) {
    const int kb = b * NKEY + p * 128 + w * 16;
    const int s = __builtin_amdgcn_readfirstlane(off3[kb]);
    const int e = __builtin_amdgcn_readfirstlane(off3[kb + 16]);
    int scur = w * 16;
    float c0 = 0.f, c1 = 0.f;
    int i = s;
    for (; i + 8 <= e; i += 8) {
      int2 p8[8];
#pragma unroll
      for (int u = 0; u < 8; ++u) p8[u] = csr2[i + u];
      unsigned q[8];
      if (act) {
#pragma unroll
        for (int u = 0; u < 8; ++u)
          q[u] = *(const unsigned*)&x[(size_t)(p8[u].x & 0x1FFFF) * XPAD + d2];
      }
#pragma unroll
      for (int u = 0; u < 8; ++u) {
        int srl = __builtin_amdgcn_readfirstlane((int)(((unsigned)p8[u].x) >> 17));
        if (srl != scur) {
          FLUSHL();
          scur = srl; c0 = 0.f; c1 = 0.f;
        }
        float v = __int_as_float(p8[u].y);
        if (act) {
          c0 += v * bflo(q[u]);
          c1 += v * bfhi(q[u]);
        }
      }
    }
    for (; i < e; ++i) {
      int2 pe = csr2[i];
      unsigned q = 0;
      if (act) q = *(const unsigned*)&x[(size_t)(pe.x & 0x1FFFF) * XPAD + d2];
      int srl = __builtin_amdgcn_readfirstlane((int)(((unsigned)pe.x) >> 17));
      if (srl != scur) {
        FLUSHL();
        scur = srl; c0 = 0.f; c1 = 0.f;
      }
      float v = __int_as_float(pe.y);
      if (act) {
        c0 += v * bflo(q);
        c1 += v * bfhi(q);
      }
    }
    FLUSHL();
  }
#undef FLUSHL

  __syncthreads();
  const int r0 = b << 7;
  for (int idx = tid; idx < 128 * 48; idx += 512) {
    int m = idx / 48;
    int l = idx - m * 48;
    int r = r0 + m;
    if (r < NN) {
      unsigned o = (unsigned)f2bf(acc[m * 96 + 2 * l]) |
                   ((unsigned)f2bf(acc[m * 96 + 2 * l + 1]) << 16);
      *(unsigned*)&ax[(size_t)r * XPAD + 2 * l] = o;
    }
  }
}

// ---- gather SpMM, D=25(32 bf16): 4 rows/wave (16-lane groups), per-row
// phase segments from off3 (same csr2; zb chunk locality for free), +b2 ----
__global__ __launch_bounds__(256) void spmm25_s(
    const int* __restrict__ off3, const int2* __restrict__ csr2,
    const unsigned short* __restrict__ zbt, const float* __restrict__ b2,
    float* __restrict__ out) {
  int gw = (int)((blockIdx.x * blockDim.x + threadIdx.x) >> 6);
  int lane = threadIdx.x & 63;
  int sub = lane >> 4;
  int d2 = (lane & 15) * 2;
  int r = gw * 4 + sub;
  if (r >= NN) return;
  const int kbase = (r >> 7) * NKEY + (r & 127);
  float a0 = 0.f, a1 = 0.f;
  for (int p = 0; p < NP; ++p) {
    int s = off3[kbase + p * 128];
    int e = off3[kbase + p * 128 + 1];
    int i = s;
    for (; i + 2 <= e; i += 2) {
      int2 p0 = csr2[i];
      int2 p1 = csr2[i + 1];
      unsigned q0 = *(const unsigned*)&zbt[(size_t)(p0.x & 0x1FFFF) * ZPAD + d2];
      unsigned q1 = *(const unsigned*)&zbt[(size_t)(p1.x & 0x1FFFF) * ZPAD + d2];
      float v0 = __int_as_float(p0.y), v1 = __int_as_float(p1.y);
      a0 += v0 * bflo(q0) + v1 * bflo(q1);
      a1 += v0 * bfhi(q0) + v1 * bfhi(q1);
    }
    if (i < e) {
      int2 pe = csr2[i];
      unsigned q = *(const unsigned*)&zbt[(size_t)(pe.x & 0x1FFFF) * ZPAD + d2];
      float v = __int_as_float(pe.y);
      a0 += v * bflo(q);
      a1 += v * bfhi(q);
    }
  }
  if (d2 < NCLS)     out[(size_t)r * NCLS + d2]     = a0 + b2[d2];
  if (d2 + 1 < NCLS) out[(size_t)r * NCLS + d2 + 1] = a1 + b2[d2 + 1];
}

// ---- Fused MLP via bf16 MFMA: z = relu(ax@W1+b1)@W2, z -> bf16[NN][32] ----
// Block = 128 nodes, 4 waves, hidden chunked x128 (8 chunks).
__global__ __launch_bounds__(256) void fused_mlp_mfma(
    const unsigned short* __restrict__ axg, const unsigned short* __restrict__ w1t,
    const float* __restrict__ b1, const unsigned short* __restrict__ w2t,
    unsigned short* __restrict__ zb) {
  __shared__ __align__(16) unsigned short axs[128 * 104];  // 26.6 KB
  __shared__ __align__(16) unsigned short hs[128 * 136];   // 34.8 KB (chunk 128)
  __shared__ float b1s[DHID];                              // 4 KB
  const int tid = threadIdx.x;
  const int n0 = blockIdx.x * 128;

  for (int idx = tid; idx < 128 * 12; idx += 256) {   // 12 sh8 chunks per row
    int m = idx / 12;
    int c8 = idx - m * 12;
    int node = n0 + m;
    sh8 v = {0, 0, 0, 0, 0, 0, 0, 0};
    if (node < NN) v = *(const sh8*)&axg[(size_t)node * XPAD + c8 * 8];
    *(sh8*)&axs[m * 104 + c8 * 8] = v;
  }
  for (int i = tid; i < DHID; i += 256) b1s[i] = b1[i];
  __syncthreads();

  const int lane = tid & 63;
  const int w = tid >> 6;
  const int quad = lane >> 4;   // A/B frag: k = quad*8 + j
  const int tn = lane & 15;     // A frag: m; B frag: n; C frag: col
  const int mta = w;            // GEMM2 m-tile 1
  const int mtb = w + 4;        // GEMM2 m-tile 2

  sh8 a1[8][3];
#pragma unroll
  for (int mt = 0; mt < 8; ++mt)
#pragma unroll
    for (int kc = 0; kc < 3; ++kc)
      a1[mt][kc] = *(const sh8*)&axs[(mt * 16 + tn) * 104 + kc * 32 + quad * 8];

  f4_t za0 = {0.f, 0.f, 0.f, 0.f}, za1 = {0.f, 0.f, 0.f, 0.f};
  f4_t zb0 = {0.f, 0.f, 0.f, 0.f}, zb1 = {0.f, 0.f, 0.f, 0.f};

  for (int c = 0; c < 8; ++c) {
    const int cb = c * 128;
    // GEMM1: wave w -> n-tiles w*2, w*2+1 ; all 8 m-tiles
#pragma unroll
    for (int nti = 0; nti < 2; ++nti) {
      const int nt = w * 2 + nti;
      const int ng = cb + nt * 16 + tn;
      const unsigned short* wr = &w1t[(size_t)ng * XPAD + quad * 8];
      sh8 b0 = *(const sh8*)&wr[0];
      sh8 b1f = *(const sh8*)&wr[32];
      sh8 b2f = *(const sh8*)&wr[64];
      float bias = b1s[ng];
#pragma unroll
      for (int mt = 0; mt < 8; ++mt) {
        f4_t acc = {0.f, 0.f, 0.f, 0.f};
        acc = __builtin_amdgcn_mfma_f32_16x16x32_bf16(a1[mt][0], b0, acc, 0, 0, 0);
        acc = __builtin_amdgcn_mfma_f32_16x16x32_bf16(a1[mt][1], b1f, acc, 0, 0, 0);
        acc = __builtin_amdgcn_mfma_f32_16x16x32_bf16(a1[mt][2], b2f, acc, 0, 0, 0);
#pragma unroll
        for (int r = 0; r < 4; ++r) {
          float v = relu_(acc[r] + bias);          // C: col=tn, row=quad*4+r
          hs[(mt * 16 + quad * 4 + r) * 136 + nt * 16 + tn] = f2bf(v);
        }
      }
    }
    __syncthreads();
    // GEMM2: z += h_chunk @ W2[cb..cb+127,:]; wave -> m-tiles w, w+4
#pragma unroll
    for (int kc = 0; kc < 4; ++kc) {
      sh8 bl = *(const sh8*)&w2t[(size_t)tn * DHID + cb + kc * 32 + quad * 8];
      sh8 bh = *(const sh8*)&w2t[(size_t)(16 + tn) * DHID + cb + kc * 32 + quad * 8];
      sh8 aa = *(const sh8*)&hs[(mta * 16 + tn) * 136 + kc * 32 + quad * 8];
      za0 = __builtin_amdgcn_mfma_f32_16x16x32_bf16(aa, bl, za0, 0, 0, 0);
      za1 = __builtin_amdgcn_mfma_f32_16x16x32_bf16(aa, bh, za1, 0, 0, 0);
      sh8 ab = *(const sh8*)&hs[(mtb * 16 + tn) * 136 + kc * 32 + quad * 8];
      zb0 = __builtin_amdgcn_mfma_f32_16x16x32_bf16(ab, bl, zb0, 0, 0, 0);
      zb1 = __builtin_amdgcn_mfma_f32_16x16x32_bf16(ab, bh, zb1, 0, 0, 0);
    }
    __syncthreads();
  }

#pragma unroll
  for (int r = 0; r < 4; ++r) {
    int na = n0 + mta * 16 + quad * 4 + r;
    if (na < NN) {
      zb[(size_t)na * ZPAD + tn]      = f2bf(za0[r]);
      zb[(size_t)na * ZPAD + 16 + tn] = f2bf(za1[r]);
    }
    int nb = n0 + mtb * 16 + quad * 4 + r;
    if (nb < NN) {
      zb[(size_t)nb * ZPAD + tn]      = f2bf(zb0[r]);
      zb[(size_t)nb * ZPAD + 16 + tn] = f2bf(zb1[r]);
    }
  }
}

extern "C" void kernel_launch(void* const* d_in, const int* in_sizes, int n_in,
                              void* d_out, int out_size, void* d_ws, size_t ws_size,
                              hipStream_t stream) {
  const float* feature = (const float*)d_in[0];
  const float* conv_w  = (const float*)d_in[1];
  const float* conv_b  = (const float*)d_in[2];
  const float* W1      = (const float*)d_in[3];
  const float* b1      = (const float*)d_in[4];
  const float* W2      = (const float*)d_in[5];
  const float* b2      = (const float*)d_in[6];
  const float* adj     = (const float*)d_in[7];
  const int*   erow    = (const int*)d_in[8];
  const int*   ecol    = (const int*)d_in[9];
  float* out = (float*)d_out;

  char* B = (char*)d_ws;
  size_t o = 0;
  auto alloc = [&](size_t bytes, size_t align) -> void* {
    o = (o + align - 1) & ~(align - 1);
    void* p = B + o;
    o += bytes;
    return p;
  };
  unsigned short* x    = (unsigned short*)alloc((size_t)NN * XPAD * 2, 16);
  unsigned short* ax   = (unsigned short*)alloc((size_t)NN * XPAD * 2, 16);
  unsigned short* zb   = (unsigned short*)alloc((size_t)NN * ZPAD * 2, 16);
  int*   gcur    = (int*)alloc((size_t)NBK * 16 * 4, 64);  // line-padded cursors
  int*   gbk     = (int*)alloc((size_t)NBK * 16 * 4, 64);  // line-padded totals
  int*   bbase   = (int*)alloc((size_t)(NBK + 1) * 4, 16); // bucket bases
  int*   off3    = (int*)alloc(((size_t)NBK * NKEY + 1) * 4, 16); // 5.2 MB
  unsigned short* w1t = (unsigned short*)alloc((size_t)DHID * XPAD * 2, 16);
  unsigned short* w2t = (unsigned short*)alloc((size_t)32 * DHID * 2, 16);
  int2*  tmp     = (int2*)alloc((size_t)EE * 8, 16);  // bucket-major
  int2*  csr2    = (int2*)alloc((size_t)EE * 8, 16);  // (bucket,chunk,row)-sorted

  // 1) x = relu(conv_sum(feature)); weight transposes + gbk zero (merged)
  conv_relu_k<<<8192, 256, 0, stream>>>(feature, conv_w, conv_b, x);
  prep_k<<<(DHID * XPAD + 255) / 256, 256, 0, stream>>>(W1, w1t, W2, w2t, gbk);
  // 2) edge build: bucket hist -> scan -> partition -> (chunk,row) counting sort
  bucket_hist_k<<<(EE + CHUNK - 1) / CHUNK, 512, 0, stream>>>(erow, gbk);
  scan_buckets_k<<<1, 1024, 0, stream>>>(gbk, bbase, gcur);
  partition_k<<<(EE + CHUNK - 1) / CHUNK, 256, 0, stream>>>(adj, erow, ecol, gcur, tmp);
  fine_scatter4_k<<<NBK, 512, 0, stream>>>(bbase, tmp, csr2, off3);
  // 3) ax = A @ x : bucket blocks, 13 column-chunk phases, LDS f32 accum
  spmm83_lds<<<NBK, 512, 0, stream>>>(off3, csr2, x, ax);
  // 4) z = relu(ax @ W1 + b1) @ W2 via bf16 MFMA (128-node tiles) -> bf16 [NN][32]
  fused_mlp_mfma<<<(NN + 127) / 128, 256, 0, stream>>>(ax, w1t, b1, w2t, zb);
  // 5) out = A @ z + b2 : per-row phase segments over the same csr2
  spmm25_s<<<(NN + 15) / 16, 256, 0, stream>>>(off3, csr2, zb, b2, out);
}

// Round 5
// 619.890 us; speedup vs baseline: 2.9128x; 1.0255x over previous
//
#include <hip/hip_runtime.h>

#define NN   100000
#define EE   3200000
#define DIN  83
#define DHID 1024
#define NCLS 25
#define XPAD 96    // x/ax bf16 row padding (192 B = 3 cache lines)
#define ZPAD 32    // z bf16 row padding (64 B = 1 cache line)

#define NBK     782   // buckets of 128 rows (row >> 7)
#define CHUNK   8192  // edges per partition block

#define CB      13            // column-chunk shift: 8192 cols = 1.57 MB of x
#define NP      13            // ceil(100000 / 8192) phases
#define NKEY    (NP * 128)    // 1664 (chunk, rowlocal) keys per bucket
#define PADK    2048          // NKEY padded to 512*4

typedef __attribute__((__ext_vector_type__(8))) short sh8;
typedef __attribute__((__ext_vector_type__(4))) float f4_t;

static __device__ __forceinline__ float relu_(float v) { return v > 0.f ? v : 0.f; }

// f32 -> bf16 (RNE)
static __device__ __forceinline__ unsigned short f2bf(float f) {
  unsigned int u = __float_as_uint(f);
  unsigned int r = u + 0x7FFFu + ((u >> 16) & 1u);
  return (unsigned short)(r >> 16);
}
// packed bf16 pair -> two f32
static __device__ __forceinline__ float bflo(unsigned int q) {
  return __uint_as_float(q << 16);
}
static __device__ __forceinline__ float bfhi(unsigned int q) {
  return __uint_as_float(q & 0xFFFF0000u);
}

// K1: Conv1d(1->4,k5,p2) + channel-sum + bias + relu -> bf16 x[NN][96]
__global__ void conv_relu_k(const float* __restrict__ feature,
                            const float* __restrict__ conv_w,
                            const float* __restrict__ conv_b,
                            unsigned short* __restrict__ x) {
  float ws0 = conv_w[0] + conv_w[5] + conv_w[10] + conv_w[15];
  float ws1 = conv_w[1] + conv_w[6] + conv_w[11] + conv_w[16];
  float ws2 = conv_w[2] + conv_w[7] + conv_w[12] + conv_w[17];
  float ws3 = conv_w[3] + conv_w[8] + conv_w[13] + conv_w[18];
  float ws4 = conv_w[4] + conv_w[9] + conv_w[14] + conv_w[19];
  float bs  = conv_b[0] + conv_b[1] + conv_b[2] + conv_b[3];
  const int total = NN * XPAD;
  for (int idx = blockIdx.x * blockDim.x + threadIdx.x; idx < total;
       idx += gridDim.x * blockDim.x) {
    int n = idx / XPAD;
    int i = idx - n * XPAD;
    unsigned short o = 0;
    if (i < DIN) {
      const float* f = feature + (size_t)n * DIN;
      float acc = bs;
      if (i >= 2)      acc += ws0 * f[i - 2];
      if (i >= 1)      acc += ws1 * f[i - 1];
      acc += ws2 * f[i];
      if (i + 1 < DIN) acc += ws3 * f[i + 1];
      if (i + 2 < DIN) acc += ws4 * f[i + 2];
      o = f2bf(relu_(acc));
    }
    x[idx] = o;
  }
}

// Combined prep: w1t transpose, w2t transpose, gbk zero
__global__ void prep_k(const float* __restrict__ W1, unsigned short* __restrict__ w1t,
                       const float* __restrict__ W2, unsigned short* __restrict__ w2t,
                       int* __restrict__ gbk) {
  int idx = blockIdx.x * blockDim.x + threadIdx.x;
  if (idx < DHID * XPAD) {            // w1t[1024][96], K zero-padded
    int k = idx / DHID;
    int n = idx - k * DHID;
    float v = (k < DIN) ? W1[k * DHID + n] : 0.f;
    w1t[n * XPAD + k] = f2bf(v);
  }
  if (idx < 32 * DHID) {              // w2t[32][1024], N zero-padded
    int k = idx / 32;
    int n = idx - k * 32;
    float v = (n < NCLS) ? W2[k * NCLS + n] : 0.f;
    w2t[n * DHID + k] = f2bf(v);
  }
  if (idx < NBK * 16) gbk[idx] = 0;
}

// ---- CSR build (bucket-hierarchical, 128-row buckets) ----

__global__ __launch_bounds__(512) void bucket_hist_k(
    const int* __restrict__ row, int* __restrict__ gbk) {
  __shared__ int cnt[NBK];
  const int tid = threadIdx.x;
  for (int b = tid; b < NBK; b += 512) cnt[b] = 0;
  __syncthreads();
  const int cb = blockIdx.x * CHUNK;
  const int csize = (cb + CHUNK <= EE) ? CHUNK : (EE - cb);
  for (int i = tid; i < csize; i += 512)
    atomicAdd(&cnt[row[cb + i] >> 7], 1);
  __syncthreads();
  for (int b = tid; b < NBK; b += 512)
    if (cnt[b]) atomicAdd(&gbk[b * 16], cnt[b]);
}

__global__ void scan_buckets_k(const int* __restrict__ gbk,
                               int* __restrict__ bbase, int* __restrict__ gcur) {
  __shared__ int sd[1024];
  int t = threadIdx.x;          // 1024 threads
  int v = (t < NBK) ? gbk[t * 16] : 0;
  sd[t] = v;
  __syncthreads();
  for (int off = 1; off < 1024; off <<= 1) {
    int add = (t >= off) ? sd[t - off] : 0;
    __syncthreads();
    sd[t] += add;
    __syncthreads();
  }
  if (t < NBK) {
    int excl = sd[t] - v;
    bbase[t] = excl;
    gcur[t * 16] = excl;   // line-padded cursor
  }
  if (t == 0) bbase[NBK] = EE;
}

// Pass 1: partition into bucket-major tmp via direct reserved-range scatter.
__global__ __launch_bounds__(256) void partition_k(
    const float* __restrict__ vals, const int* __restrict__ row,
    const int* __restrict__ col, int* __restrict__ gcur,
    int2* __restrict__ tmp) {
  __shared__ int cnt[NBK];
  __shared__ int lcur[NBK];
  const int tid = threadIdx.x;
  const int cb = blockIdx.x * CHUNK;
  const int csize = (cb + CHUNK <= EE) ? CHUNK : (EE - cb);

  for (int b = tid; b < NBK; b += 256) cnt[b] = 0;
  __syncthreads();
  for (int i = tid; i < csize; i += 256)
    atomicAdd(&cnt[row[cb + i] >> 7], 1);
  __syncthreads();
  for (int b = tid; b < NBK; b += 256)
    lcur[b] = cnt[b] ? atomicAdd(&gcur[b * 16], cnt[b]) : 0;
  __syncthreads();
  for (int i = tid; i < csize; i += 256) {
    int r = row[cb + i];
    int pos = atomicAdd(&lcur[r >> 7], 1);
    tmp[pos] = make_int2(col[cb + i] | ((r & 127) << 17),
                         __float_as_int(vals[cb + i]));
  }
}

// Pass 2: per-bucket (chunk, rowlocal) counting sort (validated round 3/4).
// csr2 globally (bucket, chunk, rowlocal)-sorted, entries keep rloc<<17;
// off3 flat monotone boundary table with sentinel EE at index NBK*NKEY.
__global__ __launch_bounds__(512) void fine_scatter4_k(
    const int* __restrict__ bbase, const int2* __restrict__ tmp,
    int2* __restrict__ csr2, int* __restrict__ off3) {
  __shared__ int cnt[PADK];    // NKEY=1664 padded to 512*4
  __shared__ int lcur[PADK];
  __shared__ int sd[512];
  const int tid = threadIdx.x;
  const int b = blockIdx.x;
  const int gstart = bbase[b];
  const int nedge = bbase[b + 1] - gstart;
  for (int k = tid; k < PADK; k += 512) cnt[k] = 0;
  __syncthreads();
  // Phase A: (chunk, rowlocal) histogram
  for (int i = tid; i < nedge; i += 512) {
    int px = tmp[gstart + i].x;
    int key = ((px & 0x1FFFF) >> CB) * 128 + (int)(((unsigned)px) >> 17);
    atomicAdd(&cnt[key], 1);
  }
  __syncthreads();
  // Phase B: exclusive scan of 2048 = 512 threads x 4 serial
  int v[4];
  int run = 0;
#pragma unroll
  for (int j = 0; j < 4; ++j) { v[j] = cnt[tid * 4 + j]; run += v[j]; }
  sd[tid] = run;
  __syncthreads();
  for (int off = 1; off < 512; off <<= 1) {
    int add = (tid >= off) ? sd[tid - off] : 0;
    __syncthreads();
    sd[tid] += add;
    __syncthreads();
  }
  int base = gstart + sd[tid] - run;
#pragma unroll
  for (int j = 0; j < 4; ++j) { cnt[tid * 4 + j] = base; base += v[j]; }
  __syncthreads();
  for (int k = tid; k < PADK; k += 512) lcur[k] = cnt[k];
  for (int k = tid; k < NKEY; k += 512) off3[b * NKEY + k] = cnt[k];
  if (b == NBK - 1 && tid == 0) off3[NBK * NKEY] = EE;
  __syncthreads();
  // Phase C: scatter within the bucket's ~32KB window (L2-local)
  for (int i = tid; i < nedge; i += 512) {
    int2 p = tmp[gstart + i];
    int key = ((p.x & 0x1FFFF) >> CB) * 128 + (int)(((unsigned)p.x) >> 17);
    int pos = atomicAdd(&lcur[key], 1);
    csr2[pos] = p;   // keep col | (rloc<<17), val
  }
}

// Pass 3: row-contiguous csr + offs/counts from csr2 (for spmm25_g).
// Writes into tmp's space (dead after fine_scatter4).
__global__ __launch_bounds__(512) void fine_row_k(
    const int* __restrict__ bbase, const int2* __restrict__ csr2,
    int2* __restrict__ csr, int* __restrict__ offs, int* __restrict__ counts) {
  __shared__ int cnt[128];
  __shared__ int sd[128];
  __shared__ int lcur[128];
  const int tid = threadIdx.x;
  const int b = blockIdx.x;
  const int gstart = bbase[b];
  const int nedge = bbase[b + 1] - gstart;
  if (tid < 128) cnt[tid] = 0;
  __syncthreads();
  for (int i = tid; i < nedge; i += 512)
    atomicAdd(&cnt[((unsigned)csr2[gstart + i].x) >> 17], 1);
  __syncthreads();
  int v = 0;
  if (tid < 128) { v = cnt[tid]; sd[tid] = v; }
  __syncthreads();
  for (int off = 1; off < 128; off <<= 1) {
    int add = (tid >= off && tid < 128) ? sd[tid - off] : 0;
    __syncthreads();
    if (tid < 128) sd[tid] += add;
    __syncthreads();
  }
  if (tid < 128) {
    int excl = gstart + sd[tid] - v;
    int r = (b << 7) + tid;
    if (r < NN) { offs[r] = excl; counts[r] = v; }
    lcur[tid] = excl;
  }
  __syncthreads();
  for (int i = tid; i < nedge; i += 512) {
    int2 p = csr2[gstart + i];
    int rl = (int)(((unsigned)p.x) >> 17);
    int pos = atomicAdd(&lcur[rl], 1);
    csr[pos] = make_int2(p.x & 0x1FFFF, p.y);
  }
}

// ---- phased gather SpMM, D=83(96 bf16): REGISTER accumulators ----
// 782 blocks x 8 waves; wave owns 16 rows -> 32 f32 accs, statically
// unrolled (all indices compile-time -> registers, no scratch).
// 13 column-chunk phases; per (phase,row) segment is contiguous in csr2
// with boundaries in off3 (vector-loaded, readlane, prefetched 1 phase
// ahead). No LDS, no atomics, no per-edge scalar branches.
__global__ __launch_bounds__(512, 6) void spmm83_ph(
    const int* __restrict__ off3, const int2* __restrict__ csr2,
    const unsigned short* __restrict__ x, unsigned short* __restrict__ ax) {
  const int b = blockIdx.x;
  const int w = threadIdx.x >> 6;
  const int lane = threadIdx.x & 63;
  const bool act = lane < 48;                 // 48 lanes x bf16-pair = 96 dims
  const int d2 = act ? lane * 2 : 0;          // idle lanes dup lane-0 addr
  float c0[16], c1[16];
#pragma unroll
  for (int k = 0; k < 16; ++k) { c0[k] = 0.f; c1[k] = 0.f; }

  const int idx17 = (lane < 17 ? lane : 16) + w * 16;
  int bv = off3[b * NKEY + idx17];            // phase-0 boundaries
  for (int p = 0; p < NP; ++p) {
    int bvn = 0;
    if (p + 1 < NP) bvn = off3[b * NKEY + (p + 1) * 128 + idx17];  // prefetch
#pragma unroll
    for (int k = 0; k < 16; ++k) {
      int s = __builtin_amdgcn_readlane(bv, k);
      int e = __builtin_amdgcn_readlane(bv, k + 1);
      float t0 = c0[k], t1 = c1[k];
      for (int i = s; i < e; ++i) {
        int2 pe = csr2[i];                    // wave-uniform -> broadcast
        unsigned q = *(const unsigned*)&x[(size_t)(pe.x & 0x1FFFF) * XPAD + d2];
        float v = __int_as_float(pe.y);
        t0 += v * bflo(q);
        t1 += v * bfhi(q);
      }
      c0[k] = t0; c1[k] = t1;
    }
    bv = bvn;
  }

  if (act) {
    const int r0 = (b << 7) + (w << 4);
#pragma unroll
    for (int k = 0; k < 16; ++k) {
      int r = r0 + k;
      if (r < NN) {
        unsigned o = (unsigned)f2bf(c0[k]) | ((unsigned)f2bf(c1[k]) << 16);
        *(unsigned*)&ax[(size_t)r * XPAD + d2] = o;
      }
    }
  }
}

// ---- gather SpMM, D=25(32 bf16): 4 rows per wave (16 lanes each), ILP-4, +b2 ----
__global__ __launch_bounds__(256) void spmm25_g(
    const int* __restrict__ offs, const int* __restrict__ cnt,
    const int2* __restrict__ csr, const unsigned short* __restrict__ zb,
    const float* __restrict__ b2, float* __restrict__ out) {
  int gw = (int)((blockIdx.x * blockDim.x + threadIdx.x) >> 6);
  int lane = threadIdx.x & 63;
  int sub = lane >> 4;
  int d2 = (lane & 15) * 2;
  int r = gw * 4 + sub;
  if (r >= NN) return;
  int s = offs[r];
  int n = cnt[r];
  float a0 = 0.f, a1 = 0.f;
  int i = 0;
  for (; i + 4 <= n; i += 4) {
    int2 p0 = csr[s + i + 0];
    int2 p1 = csr[s + i + 1];
    int2 p2 = csr[s + i + 2];
    int2 p3 = csr[s + i + 3];
    unsigned int q0 = *(const unsigned int*)&zb[(size_t)p0.x * ZPAD + d2];
    unsigned int q1 = *(const unsigned int*)&zb[(size_t)p1.x * ZPAD + d2];
    unsigned int q2 = *(const unsigned int*)&zb[(size_t)p2.x * ZPAD + d2];
    unsigned int q3 = *(const unsigned int*)&zb[(size_t)p3.x * ZPAD + d2];
    float v0 = __int_as_float(p0.y), v1 = __int_as_float(p1.y);
    float v2 = __int_as_float(p2.y), v3 = __int_as_float(p3.y);
    a0 += v0 * bflo(q0) + v1 * bflo(q1) + v2 * bflo(q2) + v3 * bflo(q3);
    a1 += v0 * bfhi(q0) + v1 * bfhi(q1) + v2 * bfhi(q2) + v3 * bfhi(q3);
  }
  for (; i < n; ++i) {
    int2 p = csr[s + i];
    unsigned int q = *(const unsigned int*)&zb[(size_t)p.x * ZPAD + d2];
    float v = __int_as_float(p.y);
    a0 += v * bflo(q);
    a1 += v * bfhi(q);
  }
  if (d2 < NCLS)     out[(size_t)r * NCLS + d2]     = a0 + b2[d2];
  if (d2 + 1 < NCLS) out[(size_t)r * NCLS + d2 + 1] = a1 + b2[d2 + 1];
}

// ---- Fused MLP via bf16 MFMA: z = relu(ax@W1+b1)@W2, z -> bf16[NN][32] ----
// Block = 128 nodes, 4 waves, hidden chunked x128 (8 chunks).
__global__ __launch_bounds__(256) void fused_mlp_mfma(
    const unsigned short* __restrict__ axg, const unsigned short* __restrict__ w1t,
    const float* __restrict__ b1, const unsigned short* __restrict__ w2t,
    unsigned short* __restrict__ zb) {
  __shared__ __align__(16) unsigned short axs[128 * 104];  // 26.6 KB
  __shared__ __align__(16) unsigned short hs[128 * 136];   // 34.8 KB (chunk 128)
  __shared__ float b1s[DHID];                              // 4 KB
  const int tid = threadIdx.x;
  const int n0 = blockIdx.x * 128;

  for (int idx = tid; idx < 128 * 12; idx += 256) {   // 12 sh8 chunks per row
    int m = idx / 12;
    int c8 = idx - m * 12;
    int node = n0 + m;
    sh8 v = {0, 0, 0, 0, 0, 0, 0, 0};
    if (node < NN) v = *(const sh8*)&axg[(size_t)node * XPAD + c8 * 8];
    *(sh8*)&axs[m * 104 + c8 * 8] = v;
  }
  for (int i = tid; i < DHID; i += 256) b1s[i] = b1[i];
  __syncthreads();

  const int lane = tid & 63;
  const int w = tid >> 6;
  const int quad = lane >> 4;   // A/B frag: k = quad*8 + j
  const int tn = lane & 15;     // A frag: m; B frag: n; C frag: col
  const int mta = w;            // GEMM2 m-tile 1
  const int mtb = w + 4;        // GEMM2 m-tile 2

  sh8 a1[8][3];
#pragma unroll
  for (int mt = 0; mt < 8; ++mt)
#pragma unroll
    for (int kc = 0; kc < 3; ++kc)
      a1[mt][kc] = *(const sh8*)&axs[(mt * 16 + tn) * 104 + kc * 32 + quad * 8];

  f4_t za0 = {0.f, 0.f, 0.f, 0.f}, za1 = {0.f, 0.f, 0.f, 0.f};
  f4_t zb0 = {0.f, 0.f, 0.f, 0.f}, zb1 = {0.f, 0.f, 0.f, 0.f};

  for (int c = 0; c < 8; ++c) {
    const int cb = c * 128;
    // GEMM1: wave w -> n-tiles w*2, w*2+1 ; all 8 m-tiles
#pragma unroll
    for (int nti = 0; nti < 2; ++nti) {
      const int nt = w * 2 + nti;
      const int ng = cb + nt * 16 + tn;
      const unsigned short* wr = &w1t[(size_t)ng * XPAD + quad * 8];
      sh8 b0 = *(const sh8*)&wr[0];
      sh8 b1f = *(const sh8*)&wr[32];
      sh8 b2f = *(const sh8*)&wr[64];
      float bias = b1s[ng];
#pragma unroll
      for (int mt = 0; mt < 8; ++mt) {
        f4_t acc = {0.f, 0.f, 0.f, 0.f};
        acc = __builtin_amdgcn_mfma_f32_16x16x32_bf16(a1[mt][0], b0, acc, 0, 0, 0);
        acc = __builtin_amdgcn_mfma_f32_16x16x32_bf16(a1[mt][1], b1f, acc, 0, 0, 0);
        acc = __builtin_amdgcn_mfma_f32_16x16x32_bf16(a1[mt][2], b2f, acc, 0, 0, 0);
#pragma unroll
        for (int r = 0; r < 4; ++r) {
          float v = relu_(acc[r] + bias);          // C: col=tn, row=quad*4+r
          hs[(mt * 16 + quad * 4 + r) * 136 + nt * 16 + tn] = f2bf(v);
        }
      }
    }
    __syncthreads();
    // GEMM2: z += h_chunk @ W2[cb..cb+127,:]; wave -> m-tiles w, w+4
#pragma unroll
    for (int kc = 0; kc < 4; ++kc) {
      sh8 bl = *(const sh8*)&w2t[(size_t)tn * DHID + cb + kc * 32 + quad * 8];
      sh8 bh = *(const sh8*)&w2t[(size_t)(16 + tn) * DHID + cb + kc * 32 + quad * 8];
      sh8 aa = *(const sh8*)&hs[(mta * 16 + tn) * 136 + kc * 32 + quad * 8];
      za0 = __builtin_amdgcn_mfma_f32_16x16x32_bf16(aa, bl, za0, 0, 0, 0);
      za1 = __builtin_amdgcn_mfma_f32_16x16x32_bf16(aa, bh, za1, 0, 0, 0);
      sh8 ab = *(const sh8*)&hs[(mtb * 16 + tn) * 136 + kc * 32 + quad * 8];
      zb0 = __builtin_amdgcn_mfma_f32_16x16x32_bf16(ab, bl, zb0, 0, 0, 0);
      zb1 = __builtin_amdgcn_mfma_f32_16x16x32_bf16(ab, bh, zb1, 0, 0, 0);
    }
    __syncthreads();
  }

#pragma unroll
  for (int r = 0; r < 4; ++r) {
    int na = n0 + mta * 16 + quad * 4 + r;
    if (na < NN) {
      zb[(size_t)na * ZPAD + tn]      = f2bf(za0[r]);
      zb[(size_t)na * ZPAD + 16 + tn] = f2bf(za1[r]);
    }
    int nb = n0 + mtb * 16 + quad * 4 + r;
    if (nb < NN) {
      zb[(size_t)nb * ZPAD + tn]      = f2bf(zb0[r]);
      zb[(size_t)nb * ZPAD + 16 + tn] = f2bf(zb1[r]);
    }
  }
}

extern "C" void kernel_launch(void* const* d_in, const int* in_sizes, int n_in,
                              void* d_out, int out_size, void* d_ws, size_t ws_size,
                              hipStream_t stream) {
  const float* feature = (const float*)d_in[0];
  const float* conv_w  = (const float*)d_in[1];
  const float* conv_b  = (const float*)d_in[2];
  const float* W1      = (const float*)d_in[3];
  const float* b1      = (const float*)d_in[4];
  const float* W2      = (const float*)d_in[5];
  const float* b2      = (const float*)d_in[6];
  const float* adj     = (const float*)d_in[7];
  const int*   erow    = (const int*)d_in[8];
  const int*   ecol    = (const int*)d_in[9];
  float* out = (float*)d_out;

  char* B = (char*)d_ws;
  size_t o = 0;
  auto alloc = [&](size_t bytes, size_t align) -> void* {
    o = (o + align - 1) & ~(align - 1);
    void* p = B + o;
    o += bytes;
    return p;
  };
  unsigned short* x    = (unsigned short*)alloc((size_t)NN * XPAD * 2, 16);
  unsigned short* ax   = (unsigned short*)alloc((size_t)NN * XPAD * 2, 16);
  unsigned short* zb   = (unsigned short*)alloc((size_t)NN * ZPAD * 2, 16);
  int*   counts  = (int*)alloc((size_t)NN * 4, 16);
  int*   offs    = (int*)alloc((size_t)NN * 4, 16);
  int*   gcur    = (int*)alloc((size_t)NBK * 16 * 4, 64);  // line-padded cursors
  int*   gbk     = (int*)alloc((size_t)NBK * 16 * 4, 64);  // line-padded totals
  int*   bbase   = (int*)alloc((size_t)(NBK + 1) * 4, 16); // bucket bases
  int*   off3    = (int*)alloc(((size_t)NBK * NKEY + 1) * 4, 16); // 5.2 MB
  unsigned short* w1t = (unsigned short*)alloc((size_t)DHID * XPAD * 2, 16);
  unsigned short* w2t = (unsigned short*)alloc((size_t)32 * DHID * 2, 16);
  int2*  tmp     = (int2*)alloc((size_t)EE * 8, 16);  // bucket-major
  int2*  csr2    = (int2*)alloc((size_t)EE * 8, 16);  // (bucket,chunk,row)-sorted
  int2*  csr     = tmp;   // row-contiguous csr overlays tmp (dead after fs4)

  // 1) x = relu(conv_sum(feature)); weight transposes + gbk zero (merged)
  conv_relu_k<<<8192, 256, 0, stream>>>(feature, conv_w, conv_b, x);
  prep_k<<<(DHID * XPAD + 255) / 256, 256, 0, stream>>>(W1, w1t, W2, w2t, gbk);
  // 2) edge build: hist -> scan -> partition -> (chunk,row) sort -> row csr
  bucket_hist_k<<<(EE + CHUNK - 1) / CHUNK, 512, 0, stream>>>(erow, gbk);
  scan_buckets_k<<<1, 1024, 0, stream>>>(gbk, bbase, gcur);
  partition_k<<<(EE + CHUNK - 1) / CHUNK, 256, 0, stream>>>(adj, erow, ecol, gcur, tmp);
  fine_scatter4_k<<<NBK, 512, 0, stream>>>(bbase, tmp, csr2, off3);
  fine_row_k<<<NBK, 512, 0, stream>>>(bbase, csr2, csr, offs, counts);
  // 3) ax = A @ x : phased gather, register accumulators, one generation
  spmm83_ph<<<NBK, 512, 0, stream>>>(off3, csr2, x, ax);
  // 4) z = relu(ax @ W1 + b1) @ W2 via bf16 MFMA (128-node tiles) -> bf16 [NN][32]
  fused_mlp_mfma<<<(NN + 127) / 128, 256, 0, stream>>>(ax, w1t, b1, w2t, zb);
  // 5) out = A @ z + b2 (gather, 1 line per edge, ILP-4)
  spmm25_g<<<(NN + 15) / 16, 256, 0, stream>>>(offs, counts, csr, zb, b2, out);
}

// Round 6
// 577.844 us; speedup vs baseline: 3.1248x; 1.0728x over previous
//
#include <hip/hip_runtime.h>

#define NN   100000
#define EE   3200000
#define DIN  83
#define DHID 1024
#define NCLS 25
#define XPAD 96    // x/ax bf16 row padding (192 B = 3 cache lines)
#define ZPAD 32    // z bf16 row padding (64 B = 1 cache line)

#define NBK     782   // buckets of 128 rows (row >> 7)
#define CHUNK   8192  // edges per partition block

#define CB      14            // column-chunk shift: 16384 cols = 3.1 MB of x
#define NP      7             // ceil(100000 / 16384) phases
#define NKEY    (NP * 128)    // 896 (chunk, rowlocal) keys per bucket
#define PADK    1024          // NKEY padded to 512*2

typedef __attribute__((__ext_vector_type__(8))) short sh8;
typedef __attribute__((__ext_vector_type__(4))) float f4_t;

static __device__ __forceinline__ float relu_(float v) { return v > 0.f ? v : 0.f; }

// f32 -> bf16 (RNE)
static __device__ __forceinline__ unsigned short f2bf(float f) {
  unsigned int u = __float_as_uint(f);
  unsigned int r = u + 0x7FFFu + ((u >> 16) & 1u);
  return (unsigned short)(r >> 16);
}
// packed bf16 pair -> two f32
static __device__ __forceinline__ float bflo(unsigned int q) {
  return __uint_as_float(q << 16);
}
static __device__ __forceinline__ float bfhi(unsigned int q) {
  return __uint_as_float(q & 0xFFFF0000u);
}

// K1: Conv1d(1->4,k5,p2) + channel-sum + bias + relu -> bf16 x[NN][96]
__global__ void conv_relu_k(const float* __restrict__ feature,
                            const float* __restrict__ conv_w,
                            const float* __restrict__ conv_b,
                            unsigned short* __restrict__ x) {
  float ws0 = conv_w[0] + conv_w[5] + conv_w[10] + conv_w[15];
  float ws1 = conv_w[1] + conv_w[6] + conv_w[11] + conv_w[16];
  float ws2 = conv_w[2] + conv_w[7] + conv_w[12] + conv_w[17];
  float ws3 = conv_w[3] + conv_w[8] + conv_w[13] + conv_w[18];
  float ws4 = conv_w[4] + conv_w[9] + conv_w[14] + conv_w[19];
  float bs  = conv_b[0] + conv_b[1] + conv_b[2] + conv_b[3];
  const int total = NN * XPAD;
  for (int idx = blockIdx.x * blockDim.x + threadIdx.x; idx < total;
       idx += gridDim.x * blockDim.x) {
    int n = idx / XPAD;
    int i = idx - n * XPAD;
    unsigned short o = 0;
    if (i < DIN) {
      const float* f = feature + (size_t)n * DIN;
      float acc = bs;
      if (i >= 2)      acc += ws0 * f[i - 2];
      if (i >= 1)      acc += ws1 * f[i - 1];
      acc += ws2 * f[i];
      if (i + 1 < DIN) acc += ws3 * f[i + 1];
      if (i + 2 < DIN) acc += ws4 * f[i + 2];
      o = f2bf(relu_(acc));
    }
    x[idx] = o;
  }
}

// Combined prep: w1t transpose, w2t transpose, gbk zero
__global__ void prep_k(const float* __restrict__ W1, unsigned short* __restrict__ w1t,
                       const float* __restrict__ W2, unsigned short* __restrict__ w2t,
                       int* __restrict__ gbk) {
  int idx = blockIdx.x * blockDim.x + threadIdx.x;
  if (idx < DHID * XPAD) {            // w1t[1024][96], K zero-padded
    int k = idx / DHID;
    int n = idx - k * DHID;
    float v = (k < DIN) ? W1[k * DHID + n] : 0.f;
    w1t[n * XPAD + k] = f2bf(v);
  }
  if (idx < 32 * DHID) {              // w2t[32][1024], N zero-padded
    int k = idx / 32;
    int n = idx - k * 32;
    float v = (n < NCLS) ? W2[k * NCLS + n] : 0.f;
    w2t[n * DHID + k] = f2bf(v);
  }
  if (idx < NBK * 16) gbk[idx] = 0;
}

// ---- CSR build (bucket-hierarchical, 128-row buckets) ----

__global__ __launch_bounds__(512) void bucket_hist_k(
    const int* __restrict__ row, int* __restrict__ gbk) {
  __shared__ int cnt[NBK];
  const int tid = threadIdx.x;
  for (int b = tid; b < NBK; b += 512) cnt[b] = 0;
  __syncthreads();
  const int cb = blockIdx.x * CHUNK;
  const int csize = (cb + CHUNK <= EE) ? CHUNK : (EE - cb);
  for (int i = tid; i < csize; i += 512)
    atomicAdd(&cnt[row[cb + i] >> 7], 1);
  __syncthreads();
  for (int b = tid; b < NBK; b += 512)
    if (cnt[b]) atomicAdd(&gbk[b * 16], cnt[b]);
}

__global__ void scan_buckets_k(const int* __restrict__ gbk,
                               int* __restrict__ bbase, int* __restrict__ gcur) {
  __shared__ int sd[1024];
  int t = threadIdx.x;          // 1024 threads
  int v = (t < NBK) ? gbk[t * 16] : 0;
  sd[t] = v;
  __syncthreads();
  for (int off = 1; off < 1024; off <<= 1) {
    int add = (t >= off) ? sd[t - off] : 0;
    __syncthreads();
    sd[t] += add;
    __syncthreads();
  }
  if (t < NBK) {
    int excl = sd[t] - v;
    bbase[t] = excl;
    gcur[t * 16] = excl;   // line-padded cursor
  }
  if (t == 0) bbase[NBK] = EE;
}

// Pass 1: partition into bucket-major tmp via direct reserved-range scatter.
__global__ __launch_bounds__(256) void partition_k(
    const float* __restrict__ vals, const int* __restrict__ row,
    const int* __restrict__ col, int* __restrict__ gcur,
    int2* __restrict__ tmp) {
  __shared__ int cnt[NBK];
  __shared__ int lcur[NBK];
  const int tid = threadIdx.x;
  const int cb = blockIdx.x * CHUNK;
  const int csize = (cb + CHUNK <= EE) ? CHUNK : (EE - cb);

  for (int b = tid; b < NBK; b += 256) cnt[b] = 0;
  __syncthreads();
  for (int i = tid; i < csize; i += 256)
    atomicAdd(&cnt[row[cb + i] >> 7], 1);
  __syncthreads();
  for (int b = tid; b < NBK; b += 256)
    lcur[b] = cnt[b] ? atomicAdd(&gcur[b * 16], cnt[b]) : 0;
  __syncthreads();
  for (int i = tid; i < csize; i += 256) {
    int r = row[cb + i];
    int pos = atomicAdd(&lcur[r >> 7], 1);
    tmp[pos] = make_int2(col[cb + i] | ((r & 127) << 17),
                         __float_as_int(vals[cb + i]));
  }
}

// Pass 2: per-bucket (chunk, rowlocal) counting sort (structure validated
// rounds 3-5; now 896 keys). csr2 globally (bucket, chunk, rowlocal)-sorted,
// entries keep rloc<<17; off3 flat monotone boundary table, sentinel EE.
__global__ __launch_bounds__(512) void fine_scatter4_k(
    const int* __restrict__ bbase, const int2* __restrict__ tmp,
    int2* __restrict__ csr2, int* __restrict__ off3) {
  __shared__ int cnt[PADK];    // NKEY=896 padded to 512*2
  __shared__ int lcur[PADK];
  __shared__ int sd[512];
  const int tid = threadIdx.x;
  const int b = blockIdx.x;
  const int gstart = bbase[b];
  const int nedge = bbase[b + 1] - gstart;
  for (int k = tid; k < PADK; k += 512) cnt[k] = 0;
  __syncthreads();
  // Phase A: (chunk, rowlocal) histogram
  for (int i = tid; i < nedge; i += 512) {
    int px = tmp[gstart + i].x;
    int key = ((px & 0x1FFFF) >> CB) * 128 + (int)(((unsigned)px) >> 17);
    atomicAdd(&cnt[key], 1);
  }
  __syncthreads();
  // Phase B: exclusive scan of 1024 = 512 threads x 2 serial
  int v0 = cnt[tid * 2], v1 = cnt[tid * 2 + 1];
  int run = v0 + v1;
  sd[tid] = run;
  __syncthreads();
  for (int off = 1; off < 512; off <<= 1) {
    int add = (tid >= off) ? sd[tid - off] : 0;
    __syncthreads();
    sd[tid] += add;
    __syncthreads();
  }
  int base = gstart + sd[tid] - run;
  cnt[tid * 2] = base;
  cnt[tid * 2 + 1] = base + v0;
  __syncthreads();
  for (int k = tid; k < PADK; k += 512) lcur[k] = cnt[k];
  for (int k = tid; k < NKEY; k += 512) off3[b * NKEY + k] = cnt[k];
  if (b == NBK - 1 && tid == 0) off3[NBK * NKEY] = EE;
  __syncthreads();
  // Phase C: scatter within the bucket's ~32KB window (L2-local)
  for (int i = tid; i < nedge; i += 512) {
    int2 p = tmp[gstart + i];
    int key = ((p.x & 0x1FFFF) >> CB) * 128 + (int)(((unsigned)p.x) >> 17);
    int pos = atomicAdd(&lcur[key], 1);
    csr2[pos] = p;   // keep col | (rloc<<17), val
  }
}

// Pass 3: row-contiguous csr + offs/counts from csr2 (for spmm25_g).
// Writes into tmp's space (dead after fine_scatter4).
__global__ __launch_bounds__(512) void fine_row_k(
    const int* __restrict__ bbase, const int2* __restrict__ csr2,
    int2* __restrict__ csr, int* __restrict__ offs, int* __restrict__ counts) {
  __shared__ int cnt[128];
  __shared__ int sd[128];
  __shared__ int lcur[128];
  const int tid = threadIdx.x;
  const int b = blockIdx.x;
  const int gstart = bbase[b];
  const int nedge = bbase[b + 1] - gstart;
  if (tid < 128) cnt[tid] = 0;
  __syncthreads();
  for (int i = tid; i < nedge; i += 512)
    atomicAdd(&cnt[((unsigned)csr2[gstart + i].x) >> 17], 1);
  __syncthreads();
  int v = 0;
  if (tid < 128) { v = cnt[tid]; sd[tid] = v; }
  __syncthreads();
  for (int off = 1; off < 128; off <<= 1) {
    int add = (tid >= off && tid < 128) ? sd[tid - off] : 0;
    __syncthreads();
    if (tid < 128) sd[tid] += add;
    __syncthreads();
  }
  if (tid < 128) {
    int excl = gstart + sd[tid] - v;
    int r = (b << 7) + tid;
    if (r < NN) { offs[r] = excl; counts[r] = v; }
    lcur[tid] = excl;
  }
  __syncthreads();
  for (int i = tid; i < nedge; i += 512) {
    int2 p = csr2[gstart + i];
    int rl = (int)(((unsigned)p.x) >> 17);
    int pos = atomicAdd(&lcur[rl], 1);
    csr[pos] = make_int2(p.x & 0x1FFFF, p.y);
  }
}

// ---- phased gather SpMM v3, D=83(96 bf16): one block per 128-row bucket.
// Wave w owns rows [16w,16w+16); per phase it walks its ~73 contiguous
// (row-sorted) edges with ILP-8 batched loads (R0 shape). Same-row runs
// (~4.6 edges at NP=7) carry in 2 registers; LDS f32 accumulator is touched
// only at run boundaries via VGPR-addressed ds RMW (no readfirstlane, no
// atomics, no scalar chain). Carries legally span batch/phase boundaries.
// Idle lanes (48-63) flush into a scratch line -> no per-edge predication.
__global__ __launch_bounds__(512, 6) void spmm83_v3(
    const int* __restrict__ off3, const int2* __restrict__ csr2,
    const unsigned short* __restrict__ x, unsigned short* __restrict__ ax) {
  __shared__ float acc[128 * 96 + 32];   // 48 KB + 128 B scratch line
  const int tid = threadIdx.x;
  const int b = blockIdx.x;
  for (int i = tid; i < 128 * 96 + 32; i += 512) acc[i] = 0.f;
  __syncthreads();
  const int w = tid >> 6;
  const int lane = tid & 63;
  const bool act = lane < 48;            // 48 lanes x bf16-pair = 96 dims
  const int d2 = act ? lane * 2 : 94;    // idle lanes dup lane-47 addr
  const int fscr = 128 * 96 + (lane - 48) * 2;  // idle-lane scratch slot

  int rlc = w * 16;                      // current run's row (wave-uniform)
  float c0 = 0.f, c1 = 0.f;              // run carry

#define EDGE_STEP(PX, PY, Q)                                        \
  do {                                                              \
    int rl_ = (int)(((unsigned)(PX)) >> 17);                        \
    float v_ = __int_as_float(PY);                                  \
    float n0_ = v_ * bflo(Q);                                       \
    float n1_ = v_ * bfhi(Q);                                       \
    if (rl_ != rlc) {                                               \
      float2* ap_ = (float2*)&acc[act ? (rlc * 96 + lane * 2) : fscr]; \
      float2 t_ = *ap_;                                             \
      t_.x += c0; t_.y += c1;                                       \
      *ap_ = t_;                                                    \
      rlc = rl_; c0 = n0_; c1 = n1_;                                \
    } else {                                                        \
      c0 += n0_; c1 += n1_;                                         \
    }                                                               \
  } while (0)

  for (int p = 0; p < NP; ++p) {
    const int kb = b * NKEY + p * 128 + w * 16;
    const int s = __builtin_amdgcn_readfirstlane(off3[kb]);
    const int e = __builtin_amdgcn_readfirstlane(off3[kb + 16]);
    int i = s;
    for (; i + 8 <= e; i += 8) {
      int2 p8[8];
#pragma unroll
      for (int u = 0; u < 8; ++u) p8[u] = csr2[i + u];
      unsigned q[8];
#pragma unroll
      for (int u = 0; u < 8; ++u)
        q[u] = *(const unsigned*)&x[(size_t)(p8[u].x & 0x1FFFF) * XPAD + d2];
#pragma unroll
      for (int u = 0; u < 8; ++u) EDGE_STEP(p8[u].x, p8[u].y, q[u]);
    }
    for (; i < e; ++i) {
      int2 pe = csr2[i];
      unsigned q = *(const unsigned*)&x[(size_t)(pe.x & 0x1FFFF) * XPAD + d2];
      EDGE_STEP(pe.x, pe.y, q);
    }
  }
  // final run flush
  {
    float2* ap = (float2*)&acc[act ? (rlc * 96 + lane * 2) : fscr];
    float2 t = *ap;
    t.x += c0; t.y += c1;
    *ap = t;
  }
#undef EDGE_STEP

  __syncthreads();
  const int r0 = b << 7;
  for (int idx = tid; idx < 128 * 48; idx += 512) {
    int m = idx / 48;
    int l = idx - m * 48;
    int r = r0 + m;
    if (r < NN) {
      unsigned o = (unsigned)f2bf(acc[m * 96 + 2 * l]) |
                   ((unsigned)f2bf(acc[m * 96 + 2 * l + 1]) << 16);
      *(unsigned*)&ax[(size_t)r * XPAD + 2 * l] = o;
    }
  }
}

// ---- gather SpMM, D=25(32 bf16): 4 rows per wave (16 lanes each), ILP-4, +b2 ----
__global__ __launch_bounds__(256) void spmm25_g(
    const int* __restrict__ offs, const int* __restrict__ cnt,
    const int2* __restrict__ csr, const unsigned short* __restrict__ zb,
    const float* __restrict__ b2, float* __restrict__ out) {
  int gw = (int)((blockIdx.x * blockDim.x + threadIdx.x) >> 6);
  int lane = threadIdx.x & 63;
  int sub = lane >> 4;
  int d2 = (lane & 15) * 2;
  int r = gw * 4 + sub;
  if (r >= NN) return;
  int s = offs[r];
  int n = cnt[r];
  float a0 = 0.f, a1 = 0.f;
  int i = 0;
  for (; i + 4 <= n; i += 4) {
    int2 p0 = csr[s + i + 0];
    int2 p1 = csr[s + i + 1];
    int2 p2 = csr[s + i + 2];
    int2 p3 = csr[s + i + 3];
    unsigned int q0 = *(const unsigned int*)&zb[(size_t)p0.x * ZPAD + d2];
    unsigned int q1 = *(const unsigned int*)&zb[(size_t)p1.x * ZPAD + d2];
    unsigned int q2 = *(const unsigned int*)&zb[(size_t)p2.x * ZPAD + d2];
    unsigned int q3 = *(const unsigned int*)&zb[(size_t)p3.x * ZPAD + d2];
    float v0 = __int_as_float(p0.y), v1 = __int_as_float(p1.y);
    float v2 = __int_as_float(p2.y), v3 = __int_as_float(p3.y);
    a0 += v0 * bflo(q0) + v1 * bflo(q1) + v2 * bflo(q2) + v3 * bflo(q3);
    a1 += v0 * bfhi(q0) + v1 * bfhi(q1) + v2 * bfhi(q2) + v3 * bfhi(q3);
  }
  for (; i < n; ++i) {
    int2 p = csr[s + i];
    unsigned int q = *(const unsigned int*)&zb[(size_t)p.x * ZPAD + d2];
    float v = __int_as_float(p.y);
    a0 += v * bflo(q);
    a1 += v * bfhi(q);
  }
  if (d2 < NCLS)     out[(size_t)r * NCLS + d2]     = a0 + b2[d2];
  if (d2 + 1 < NCLS) out[(size_t)r * NCLS + d2 + 1] = a1 + b2[d2 + 1];
}

// ---- Fused MLP via bf16 MFMA: z = relu(ax@W1+b1)@W2, z -> bf16[NN][32] ----
// Block = 128 nodes, 4 waves, hidden chunked x128 (8 chunks).
__global__ __launch_bounds__(256) void fused_mlp_mfma(
    const unsigned short* __restrict__ axg, const unsigned short* __restrict__ w1t,
    const float* __restrict__ b1, const unsigned short* __restrict__ w2t,
    unsigned short* __restrict__ zb) {
  __shared__ __align__(16) unsigned short axs[128 * 104];  // 26.6 KB
  __shared__ __align__(16) unsigned short hs[128 * 136];   // 34.8 KB (chunk 128)
  __shared__ float b1s[DHID];                              // 4 KB
  const int tid = threadIdx.x;
  const int n0 = blockIdx.x * 128;

  for (int idx = tid; idx < 128 * 12; idx += 256) {   // 12 sh8 chunks per row
    int m = idx / 12;
    int c8 = idx - m * 12;
    int node = n0 + m;
    sh8 v = {0, 0, 0, 0, 0, 0, 0, 0};
    if (node < NN) v = *(const sh8*)&axg[(size_t)node * XPAD + c8 * 8];
    *(sh8*)&axs[m * 104 + c8 * 8] = v;
  }
  for (int i = tid; i < DHID; i += 256) b1s[i] = b1[i];
  __syncthreads();

  const int lane = tid & 63;
  const int w = tid >> 6;
  const int quad = lane >> 4;   // A/B frag: k = quad*8 + j
  const int tn = lane & 15;     // A frag: m; B frag: n; C frag: col
  const int mta = w;            // GEMM2 m-tile 1
  const int mtb = w + 4;        // GEMM2 m-tile 2

  sh8 a1[8][3];
#pragma unroll
  for (int mt = 0; mt < 8; ++mt)
#pragma unroll
    for (int kc = 0; kc < 3; ++kc)
      a1[mt][kc] = *(const sh8*)&axs[(mt * 16 + tn) * 104 + kc * 32 + quad * 8];

  f4_t za0 = {0.f, 0.f, 0.f, 0.f}, za1 = {0.f, 0.f, 0.f, 0.f};
  f4_t zb0 = {0.f, 0.f, 0.f, 0.f}, zb1 = {0.f, 0.f, 0.f, 0.f};

  for (int c = 0; c < 8; ++c) {
    const int cb = c * 128;
    // GEMM1: wave w -> n-tiles w*2, w*2+1 ; all 8 m-tiles
#pragma unroll
    for (int nti = 0; nti < 2; ++nti) {
      const int nt = w * 2 + nti;
      const int ng = cb + nt * 16 + tn;
      const unsigned short* wr = &w1t[(size_t)ng * XPAD + quad * 8];
      sh8 b0 = *(const sh8*)&wr[0];
      sh8 b1f = *(const sh8*)&wr[32];
      sh8 b2f = *(const sh8*)&wr[64];
      float bias = b1s[ng];
#pragma unroll
      for (int mt = 0; mt < 8; ++mt) {
        f4_t acc = {0.f, 0.f, 0.f, 0.f};
        acc = __builtin_amdgcn_mfma_f32_16x16x32_bf16(a1[mt][0], b0, acc, 0, 0, 0);
        acc = __builtin_amdgcn_mfma_f32_16x16x32_bf16(a1[mt][1], b1f, acc, 0, 0, 0);
        acc = __builtin_amdgcn_mfma_f32_16x16x32_bf16(a1[mt][2], b2f, acc, 0, 0, 0);
#pragma unroll
        for (int r = 0; r < 4; ++r) {
          float v = relu_(acc[r] + bias);          // C: col=tn, row=quad*4+r
          hs[(mt * 16 + quad * 4 + r) * 136 + nt * 16 + tn] = f2bf(v);
        }
      }
    }
    __syncthreads();
    // GEMM2: z += h_chunk @ W2[cb..cb+127,:]; wave -> m-tiles w, w+4
#pragma unroll
    for (int kc = 0; kc < 4; ++kc) {
      sh8 bl = *(const sh8*)&w2t[(size_t)tn * DHID + cb + kc * 32 + quad * 8];
      sh8 bh = *(const sh8*)&w2t[(size_t)(16 + tn) * DHID + cb + kc * 32 + quad * 8];
      sh8 aa = *(const sh8*)&hs[(mta * 16 + tn) * 136 + kc * 32 + quad * 8];
      za0 = __builtin_amdgcn_mfma_f32_16x16x32_bf16(aa, bl, za0, 0, 0, 0);
      za1 = __builtin_amdgcn_mfma_f32_16x16x32_bf16(aa, bh, za1, 0, 0, 0);
      sh8 ab = *(const sh8*)&hs[(mtb * 16 + tn) * 136 + kc * 32 + quad * 8];
      zb0 = __builtin_amdgcn_mfma_f32_16x16x32_bf16(ab, bl, zb0, 0, 0, 0);
      zb1 = __builtin_amdgcn_mfma_f32_16x16x32_bf16(ab, bh, zb1, 0, 0, 0);
    }
    __syncthreads();
  }

#pragma unroll
  for (int r = 0; r < 4; ++r) {
    int na = n0 + mta * 16 + quad * 4 + r;
    if (na < NN) {
      zb[(size_t)na * ZPAD + tn]      = f2bf(za0[r]);
      zb[(size_t)na * ZPAD + 16 + tn] = f2bf(za1[r]);
    }
    int nb = n0 + mtb * 16 + quad * 4 + r;
    if (nb < NN) {
      zb[(size_t)nb * ZPAD + tn]      = f2bf(zb0[r]);
      zb[(size_t)nb * ZPAD + 16 + tn] = f2bf(zb1[r]);
    }
  }
}

extern "C" void kernel_launch(void* const* d_in, const int* in_sizes, int n_in,
                              void* d_out, int out_size, void* d_ws, size_t ws_size,
                              hipStream_t stream) {
  const float* feature = (const float*)d_in[0];
  const float* conv_w  = (const float*)d_in[1];
  const float* conv_b  = (const float*)d_in[2];
  const float* W1      = (const float*)d_in[3];
  const float* b1      = (const float*)d_in[4];
  const float* W2      = (const float*)d_in[5];
  const float* b2      = (const float*)d_in[6];
  const float* adj     = (const float*)d_in[7];
  const int*   erow    = (const int*)d_in[8];
  const int*   ecol    = (const int*)d_in[9];
  float* out = (float*)d_out;

  char* B = (char*)d_ws;
  size_t o = 0;
  auto alloc = [&](size_t bytes, size_t align) -> void* {
    o = (o + align - 1) & ~(align - 1);
    void* p = B + o;
    o += bytes;
    return p;
  };
  unsigned short* x    = (unsigned short*)alloc((size_t)NN * XPAD * 2, 16);
  unsigned short* ax   = (unsigned short*)alloc((size_t)NN * XPAD * 2, 16);
  unsigned short* zb   = (unsigned short*)alloc((size_t)NN * ZPAD * 2, 16);
  int*   counts  = (int*)alloc((size_t)NN * 4, 16);
  int*   offs    = (int*)alloc((size_t)NN * 4, 16);
  int*   gcur    = (int*)alloc((size_t)NBK * 16 * 4, 64);  // line-padded cursors
  int*   gbk     = (int*)alloc((size_t)NBK * 16 * 4, 64);  // line-padded totals
  int*   bbase   = (int*)alloc((size_t)(NBK + 1) * 4, 16); // bucket bases
  int*   off3    = (int*)alloc(((size_t)NBK * NKEY + 1) * 4, 16); // 2.8 MB
  unsigned short* w1t = (unsigned short*)alloc((size_t)DHID * XPAD * 2, 16);
  unsigned short* w2t = (unsigned short*)alloc((size_t)32 * DHID * 2, 16);
  int2*  tmp     = (int2*)alloc((size_t)EE * 8, 16);  // bucket-major
  int2*  csr2    = (int2*)alloc((size_t)EE * 8, 16);  // (bucket,chunk,row)-sorted
  int2*  csr     = tmp;   // row-contiguous csr overlays tmp (dead after fs4)

  // 1) x = relu(conv_sum(feature)); weight transposes + gbk zero (merged)
  conv_relu_k<<<8192, 256, 0, stream>>>(feature, conv_w, conv_b, x);
  prep_k<<<(DHID * XPAD + 255) / 256, 256, 0, stream>>>(W1, w1t, W2, w2t, gbk);
  // 2) edge build: hist -> scan -> partition -> (chunk,row) sort -> row csr
  bucket_hist_k<<<(EE + CHUNK - 1) / CHUNK, 512, 0, stream>>>(erow, gbk);
  scan_buckets_k<<<1, 1024, 0, stream>>>(gbk, bbase, gcur);
  partition_k<<<(EE + CHUNK - 1) / CHUNK, 256, 0, stream>>>(adj, erow, ecol, gcur, tmp);
  fine_scatter4_k<<<NBK, 512, 0, stream>>>(bbase, tmp, csr2, off3);
  fine_row_k<<<NBK, 512, 0, stream>>>(bbase, csr2, csr, offs, counts);
  // 3) ax = A @ x : phased ILP-8 gather, run-carry regs, LDS boundary flush
  spmm83_v3<<<NBK, 512, 0, stream>>>(off3, csr2, x, ax);
  // 4) z = relu(ax @ W1 + b1) @ W2 via bf16 MFMA (128-node tiles) -> bf16 [NN][32]
  fused_mlp_mfma<<<(NN + 127) / 128, 256, 0, stream>>>(ax, w1t, b1, w2t, zb);
  // 5) out = A @ z + b2 (gather, 1 line per edge, ILP-4)
  spmm25_g<<<(NN + 15) / 16, 256, 0, stream>>>(offs, counts, csr, zb, b2, out);
}

// Round 7
// 460.134 us; speedup vs baseline: 3.9241x; 1.2558x over previous
//
#include <hip/hip_runtime.h>

#define NN   100000
#define EE   3200000
#define DIN  83
#define DHID 1024
#define NCLS 25
#define XPAD 96    // x/ax bf16 row padding (192 B = 3 cache lines)
#define ZPAD 32    // z bf16 row padding (64 B = 1 cache line)

#define NBK     391   // buckets of 256 rows (row >> 8)
#define CHUNK   8192  // edges per partition block

typedef __attribute__((__ext_vector_type__(8))) short sh8;
typedef __attribute__((__ext_vector_type__(4))) float f4_t;

static __device__ __forceinline__ float relu_(float v) { return v > 0.f ? v : 0.f; }

// f32 -> bf16 (RNE)
static __device__ __forceinline__ unsigned short f2bf(float f) {
  unsigned int u = __float_as_uint(f);
  unsigned int r = u + 0x7FFFu + ((u >> 16) & 1u);
  return (unsigned short)(r >> 16);
}
// packed bf16 pair -> two f32
static __device__ __forceinline__ float bflo(unsigned int q) {
  return __uint_as_float(q << 16);
}
static __device__ __forceinline__ float bfhi(unsigned int q) {
  return __uint_as_float(q & 0xFFFF0000u);
}

// K1: Conv1d(1->4,k5,p2) + channel-sum + bias + relu -> bf16 x[NN][96]
// Vectorized: one thread per (node, 8-dim group): 12 scalar loads -> 8 outs,
// one 16B sh8 store (vs 5 loads + 2B store per output before).
__global__ __launch_bounds__(256) void conv_relu_k(
    const float* __restrict__ feature, const float* __restrict__ conv_w,
    const float* __restrict__ conv_b, unsigned short* __restrict__ x) {
  float ws0 = conv_w[0] + conv_w[5] + conv_w[10] + conv_w[15];
  float ws1 = conv_w[1] + conv_w[6] + conv_w[11] + conv_w[16];
  float ws2 = conv_w[2] + conv_w[7] + conv_w[12] + conv_w[17];
  float ws3 = conv_w[3] + conv_w[8] + conv_w[13] + conv_w[18];
  float ws4 = conv_w[4] + conv_w[9] + conv_w[14] + conv_w[19];
  float bs  = conv_b[0] + conv_b[1] + conv_b[2] + conv_b[3];
  int t = blockIdx.x * 256 + threadIdx.x;
  if (t >= NN * 12) return;
  int n = t / 12;
  int g = t - n * 12;
  int i0 = g * 8;
  const float* f = feature + (size_t)n * DIN;
  float fv[12];
#pragma unroll
  for (int k = 0; k < 12; ++k) {
    int idx = i0 - 2 + k;
    fv[k] = (idx >= 0 && idx < DIN) ? f[idx] : 0.f;
  }
  sh8 vout;
#pragma unroll
  for (int j = 0; j < 8; ++j) {
    int i = i0 + j;
    unsigned short o = 0;
    if (i < DIN) {
      float acc = bs + ws0 * fv[j] + ws1 * fv[j + 1] + ws2 * fv[j + 2] +
                  ws3 * fv[j + 3] + ws4 * fv[j + 4];
      o = f2bf(relu_(acc));
    }
    vout[j] = (short)o;
  }
  *(sh8*)&x[(size_t)n * XPAD + i0] = vout;
}

// Combined prep: w1t transpose, w2t transpose, gbk zero
__global__ void prep_k(const float* __restrict__ W1, unsigned short* __restrict__ w1t,
                       const float* __restrict__ W2, unsigned short* __restrict__ w2t,
                       int* __restrict__ gbk) {
  int idx = blockIdx.x * blockDim.x + threadIdx.x;
  if (idx < DHID * XPAD) {            // w1t[1024][96], K zero-padded
    int k = idx / DHID;
    int n = idx - k * DHID;
    float v = (k < DIN) ? W1[k * DHID + n] : 0.f;
    w1t[n * XPAD + k] = f2bf(v);
  }
  if (idx < 32 * DHID) {              // w2t[32][1024], N zero-padded
    int k = idx / 32;
    int n = idx - k * 32;
    float v = (n < NCLS) ? W2[k * NCLS + n] : 0.f;
    w2t[n * DHID + k] = f2bf(v);
  }
  if (idx < NBK * 16) gbk[idx] = 0;
}

// ---- CSR build (bucket-hierarchical) ----

__global__ __launch_bounds__(512) void bucket_hist_k(
    const int* __restrict__ row, int* __restrict__ gbk) {
  __shared__ int cnt[NBK];
  const int tid = threadIdx.x;
  for (int b = tid; b < NBK; b += 512) cnt[b] = 0;
  __syncthreads();
  const int cb = blockIdx.x * CHUNK;
  const int csize = (cb + CHUNK <= EE) ? CHUNK : (EE - cb);
  for (int i = tid; i < csize; i += 512)
    atomicAdd(&cnt[row[cb + i] >> 8], 1);
  __syncthreads();
  for (int b = tid; b < NBK; b += 512)
    if (cnt[b]) atomicAdd(&gbk[b * 16], cnt[b]);
}

__global__ void scan_buckets_k(const int* __restrict__ gbk,
                               int* __restrict__ bbase, int* __restrict__ gcur) {
  __shared__ int sd[512];
  int t = threadIdx.x;
  int v = (t < NBK) ? gbk[t * 16] : 0;
  sd[t] = v;
  __syncthreads();
  for (int off = 1; off < 512; off <<= 1) {
    int add = (t >= off) ? sd[t - off] : 0;
    __syncthreads();
    sd[t] += add;
    __syncthreads();
  }
  if (t < NBK) {
    int excl = sd[t] - v;
    bbase[t] = excl;
    gcur[t * 16] = excl;   // line-padded cursor
  }
  if (t == 0) bbase[NBK] = EE;
}

// Pass 1: partition into bucket-major tmp via direct reserved-range scatter.
__global__ __launch_bounds__(256) void partition_k(
    const float* __restrict__ vals, const int* __restrict__ row,
    const int* __restrict__ col, int* __restrict__ gcur,
    int2* __restrict__ tmp) {
  __shared__ int cnt[NBK];
  __shared__ int lcur[NBK];
  const int tid = threadIdx.x;
  const int cb = blockIdx.x * CHUNK;
  const int csize = (cb + CHUNK <= EE) ? CHUNK : (EE - cb);

  for (int b = tid; b < NBK; b += 256) cnt[b] = 0;
  __syncthreads();
  for (int i = tid; i < csize; i += 256)
    atomicAdd(&cnt[row[cb + i] >> 8], 1);
  __syncthreads();
  for (int b = tid; b < NBK; b += 256)
    lcur[b] = cnt[b] ? atomicAdd(&gcur[b * 16], cnt[b]) : 0;
  __syncthreads();
  for (int i = tid; i < csize; i += 256) {
    int r = row[cb + i];
    int pos = atomicAdd(&lcur[r >> 8], 1);
    tmp[pos] = make_int2(col[cb + i] | ((r & 255) << 17),
                         __float_as_int(vals[cb + i]));
  }
}

// Pass 2: per-bucket fine scatter + per-row offset derivation (512 threads).
__global__ __launch_bounds__(512) void fine_scatter2_k(
    const int* __restrict__ bbase, const int2* __restrict__ tmp,
    int2* __restrict__ csr, int* __restrict__ offs, int* __restrict__ counts) {
  __shared__ int cnt[256];
  __shared__ int sd[256];
  __shared__ int lcur[256];
  const int tid = threadIdx.x;
  const int b = blockIdx.x;
  const int r0 = b * 256;
  const int gstart = bbase[b];
  const int nedge = bbase[b + 1] - gstart;
  if (tid < 256) cnt[tid] = 0;
  __syncthreads();
  // Phase A: per-row histogram (LDS atomics)
  for (int i = tid; i < nedge; i += 512)
    atomicAdd(&cnt[((unsigned)tmp[gstart + i].x) >> 17], 1);
  __syncthreads();
  // Phase B: exclusive scan of 256 row counts (first 256 threads)
  int v = 0;
  if (tid < 256) { v = cnt[tid]; sd[tid] = v; }
  __syncthreads();
  for (int off = 1; off < 256; off <<= 1) {
    int add = (tid >= off && tid < 256) ? sd[tid - off] : 0;
    __syncthreads();
    if (tid < 256) sd[tid] += add;
    __syncthreads();
  }
  if (tid < 256) {
    int excl = gstart + sd[tid] - v;
    int r = r0 + tid;
    if (r < NN) {
      offs[r] = excl;
      counts[r] = v;
    }
    lcur[tid] = excl;
  }
  __syncthreads();
  // Phase C: scatter within the bucket's window (L2-local)
  for (int i = tid; i < nedge; i += 512) {
    int2 p = tmp[gstart + i];
    int rl = ((unsigned)p.x) >> 17;
    int pos = atomicAdd(&lcur[rl], 1);
    csr[pos] = make_int2(p.x & 0x1FFFF, p.y);
  }
}

// ---- gather SpMM, D=83(96 bf16): one wave per row, ILP-8, scalar edge loads.
// Declared local roofline: fill-path-bound at ~3.8 TB/s on 343 MB of random
// 64B-line L2-miss fills (92% of the 90 µs floor). Byte-reduction variants
// (LDS atomics / scalar flush / segment regs / vector flush) all measured
// net-negative; csr loads already SGPR-scalarized (VGPR_Count=12).
__global__ __launch_bounds__(256) void spmm83_g(
    const int* __restrict__ offs, const int* __restrict__ cnt,
    const int2* __restrict__ csr, const unsigned short* __restrict__ x,
    unsigned short* __restrict__ ax) {
  int wave = (int)((blockIdx.x * blockDim.x + threadIdx.x) >> 6);
  int lane = threadIdx.x & 63;
  if (wave >= NN) return;
  int s = __builtin_amdgcn_readfirstlane(offs[wave]);   // wave-uniform -> SGPR
  int n = __builtin_amdgcn_readfirstlane(cnt[wave]);
  const bool act = lane < 48;         // 48 lanes x short2 = 96 dims
  const int d2 = lane * 2;
  float a0 = 0.f, a1 = 0.f;
  int i = 0;
  for (; i + 8 <= n; i += 8) {
    int2 p[8];
#pragma unroll
    for (int u = 0; u < 8; ++u) p[u] = csr[s + i + u];
    if (act) {
      unsigned int q[8];
#pragma unroll
      for (int u = 0; u < 8; ++u)
        q[u] = *(const unsigned int*)&x[(size_t)p[u].x * XPAD + d2];
#pragma unroll
      for (int u = 0; u < 8; ++u) {
        float v = __int_as_float(p[u].y);
        a0 += v * bflo(q[u]);
        a1 += v * bfhi(q[u]);
      }
    }
  }
  for (; i < n; ++i) {
    int2 p = csr[s + i];
    if (act) {
      unsigned int q = *(const unsigned int*)&x[(size_t)p.x * XPAD + d2];
      float v = __int_as_float(p.y);
      a0 += v * bflo(q);
      a1 += v * bfhi(q);
    }
  }
  if (act) {
    unsigned int o = (unsigned int)f2bf(a0) | ((unsigned int)f2bf(a1) << 16);
    *(unsigned int*)&ax[(size_t)wave * XPAD + d2] = o;
  }
}

// ---- gather SpMM, D=25(32 bf16): 4 rows per wave (16 lanes each), ILP-8, +b2 ----
__global__ __launch_bounds__(256) void spmm25_g(
    const int* __restrict__ offs, const int* __restrict__ cnt,
    const int2* __restrict__ csr, const unsigned short* __restrict__ zb,
    const float* __restrict__ b2, float* __restrict__ out) {
  int gw = (int)((blockIdx.x * blockDim.x + threadIdx.x) >> 6);
  int lane = threadIdx.x & 63;
  int sub = lane >> 4;
  int d2 = (lane & 15) * 2;
  int r = gw * 4 + sub;
  if (r >= NN) return;
  int s = offs[r];
  int n = cnt[r];
  float a0 = 0.f, a1 = 0.f;
  int i = 0;
  for (; i + 8 <= n; i += 8) {
    int2 p[8];
#pragma unroll
    for (int u = 0; u < 8; ++u) p[u] = csr[s + i + u];
    unsigned int q[8];
#pragma unroll
    for (int u = 0; u < 8; ++u)
      q[u] = *(const unsigned int*)&zb[(size_t)p[u].x * ZPAD + d2];
#pragma unroll
    for (int u = 0; u < 8; ++u) {
      float v = __int_as_float(p[u].y);
      a0 += v * bflo(q[u]);
      a1 += v * bfhi(q[u]);
    }
  }
  for (; i < n; ++i) {
    int2 p = csr[s + i];
    unsigned int q = *(const unsigned int*)&zb[(size_t)p.x * ZPAD + d2];
    float v = __int_as_float(p.y);
    a0 += v * bflo(q);
    a1 += v * bfhi(q);
  }
  if (d2 < NCLS)     out[(size_t)r * NCLS + d2]     = a0 + b2[d2];
  if (d2 + 1 < NCLS) out[(size_t)r * NCLS + d2 + 1] = a1 + b2[d2 + 1];
}

// ---- Fused MLP via bf16 MFMA: z = relu(ax@W1+b1)@W2, z -> bf16[NN][32] ----
// Block = 128 nodes, 4 waves, hidden chunked x128 (8 chunks).
__global__ __launch_bounds__(256) void fused_mlp_mfma(
    const unsigned short* __restrict__ axg, const unsigned short* __restrict__ w1t,
    const float* __restrict__ b1, const unsigned short* __restrict__ w2t,
    unsigned short* __restrict__ zb) {
  __shared__ __align__(16) unsigned short axs[128 * 104];  // 26.6 KB
  __shared__ __align__(16) unsigned short hs[128 * 136];   // 34.8 KB (chunk 128)
  __shared__ float b1s[DHID];                              // 4 KB
  const int tid = threadIdx.x;
  const int n0 = blockIdx.x * 128;

  for (int idx = tid; idx < 128 * 12; idx += 256) {   // 12 sh8 chunks per row
    int m = idx / 12;
    int c8 = idx - m * 12;
    int node = n0 + m;
    sh8 v = {0, 0, 0, 0, 0, 0, 0, 0};
    if (node < NN) v = *(const sh8*)&axg[(size_t)node * XPAD + c8 * 8];
    *(sh8*)&axs[m * 104 + c8 * 8] = v;
  }
  for (int i = tid; i < DHID; i += 256) b1s[i] = b1[i];
  __syncthreads();

  const int lane = tid & 63;
  const int w = tid >> 6;
  const int quad = lane >> 4;   // A/B frag: k = quad*8 + j
  const int tn = lane & 15;     // A frag: m; B frag: n; C frag: col
  const int mta = w;            // GEMM2 m-tile 1
  const int mtb = w + 4;        // GEMM2 m-tile 2

  sh8 a1[8][3];
#pragma unroll
  for (int mt = 0; mt < 8; ++mt)
#pragma unroll
    for (int kc = 0; kc < 3; ++kc)
      a1[mt][kc] = *(const sh8*)&axs[(mt * 16 + tn) * 104 + kc * 32 + quad * 8];

  f4_t za0 = {0.f, 0.f, 0.f, 0.f}, za1 = {0.f, 0.f, 0.f, 0.f};
  f4_t zb0 = {0.f, 0.f, 0.f, 0.f}, zb1 = {0.f, 0.f, 0.f, 0.f};

  for (int c = 0; c < 8; ++c) {
    const int cb = c * 128;
    // GEMM1: wave w -> n-tiles w*2, w*2+1 ; all 8 m-tiles
#pragma unroll
    for (int nti = 0; nti < 2; ++nti) {
      const int nt = w * 2 + nti;
      const int ng = cb + nt * 16 + tn;
      const unsigned short* wr = &w1t[(size_t)ng * XPAD + quad * 8];
      sh8 b0 = *(const sh8*)&wr[0];
      sh8 b1f = *(const sh8*)&wr[32];
      sh8 b2f = *(const sh8*)&wr[64];
      float bias = b1s[ng];
#pragma unroll
      for (int mt = 0; mt < 8; ++mt) {
        f4_t acc = {0.f, 0.f, 0.f, 0.f};
        acc = __builtin_amdgcn_mfma_f32_16x16x32_bf16(a1[mt][0], b0, acc, 0, 0, 0);
        acc = __builtin_amdgcn_mfma_f32_16x16x32_bf16(a1[mt][1], b1f, acc, 0, 0, 0);
        acc = __builtin_amdgcn_mfma_f32_16x16x32_bf16(a1[mt][2], b2f, acc, 0, 0, 0);
#pragma unroll
        for (int r = 0; r < 4; ++r) {
          float v = relu_(acc[r] + bias);          // C: col=tn, row=quad*4+r
          hs[(mt * 16 + quad * 4 + r) * 136 + nt * 16 + tn] = f2bf(v);
        }
      }
    }
    __syncthreads();
    // GEMM2: z += h_chunk @ W2[cb..cb+127,:]; wave -> m-tiles w, w+4
#pragma unroll
    for (int kc = 0; kc < 4; ++kc) {
      sh8 bl = *(const sh8*)&w2t[(size_t)tn * DHID + cb + kc * 32 + quad * 8];
      sh8 bh = *(const sh8*)&w2t[(size_t)(16 + tn) * DHID + cb + kc * 32 + quad * 8];
      sh8 aa = *(const sh8*)&hs[(mta * 16 + tn) * 136 + kc * 32 + quad * 8];
      za0 = __builtin_amdgcn_mfma_f32_16x16x32_bf16(aa, bl, za0, 0, 0, 0);
      za1 = __builtin_amdgcn_mfma_f32_16x16x32_bf16(aa, bh, za1, 0, 0, 0);
      sh8 ab = *(const sh8*)&hs[(mtb * 16 + tn) * 136 + kc * 32 + quad * 8];
      zb0 = __builtin_amdgcn_mfma_f32_16x16x32_bf16(ab, bl, zb0, 0, 0, 0);
      zb1 = __builtin_amdgcn_mfma_f32_16x16x32_bf16(ab, bh, zb1, 0, 0, 0);
    }
    __syncthreads();
  }

#pragma unroll
  for (int r = 0; r < 4; ++r) {
    int na = n0 + mta * 16 + quad * 4 + r;
    if (na < NN) {
      zb[(size_t)na * ZPAD + tn]      = f2bf(za0[r]);
      zb[(size_t)na * ZPAD + 16 + tn] = f2bf(za1[r]);
    }
    int nb = n0 + mtb * 16 + quad * 4 + r;
    if (nb < NN) {
      zb[(size_t)nb * ZPAD + tn]      = f2bf(zb0[r]);
      zb[(size_t)nb * ZPAD + 16 + tn] = f2bf(zb1[r]);
    }
  }
}

extern "C" void kernel_launch(void* const* d_in, const int* in_sizes, int n_in,
                              void* d_out, int out_size, void* d_ws, size_t ws_size,
                              hipStream_t stream) {
  const float* feature = (const float*)d_in[0];
  const float* conv_w  = (const float*)d_in[1];
  const float* conv_b  = (const float*)d_in[2];
  const float* W1      = (const float*)d_in[3];
  const float* b1      = (const float*)d_in[4];
  const float* W2      = (const float*)d_in[5];
  const float* b2      = (const float*)d_in[6];
  const float* adj     = (const float*)d_in[7];
  const int*   erow    = (const int*)d_in[8];
  const int*   ecol    = (const int*)d_in[9];
  float* out = (float*)d_out;

  char* B = (char*)d_ws;
  size_t o = 0;
  auto alloc = [&](size_t bytes, size_t align) -> void* {
    o = (o + align - 1) & ~(align - 1);
    void* p = B + o;
    o += bytes;
    return p;
  };
  unsigned short* x    = (unsigned short*)alloc((size_t)NN * XPAD * 2, 16);
  unsigned short* ax   = (unsigned short*)alloc((size_t)NN * XPAD * 2, 16);
  unsigned short* zb   = (unsigned short*)alloc((size_t)NN * ZPAD * 2, 16);
  int*   counts  = (int*)alloc((size_t)NN * 4, 16);
  int*   offs    = (int*)alloc((size_t)NN * 4, 16);
  int*   gcur    = (int*)alloc((size_t)NBK * 16 * 4, 64);  // line-padded cursors
  int*   gbk     = (int*)alloc((size_t)NBK * 16 * 4, 64);  // line-padded totals
  int*   bbase   = (int*)alloc((size_t)(NBK + 1) * 4, 16); // bucket bases
  unsigned short* w1t = (unsigned short*)alloc((size_t)DHID * XPAD * 2, 16);
  unsigned short* w2t = (unsigned short*)alloc((size_t)32 * DHID * 2, 16);
  int2*  tmp     = (int2*)alloc((size_t)EE * 8, 16);  // bucket-major
  int2*  csr     = (int2*)alloc((size_t)EE * 8, 16);  // row-sorted

  // 1) x = relu(conv_sum(feature)); weight transposes + gbk zero (merged)
  conv_relu_k<<<(NN * 12 + 255) / 256, 256, 0, stream>>>(feature, conv_w, conv_b, x);
  prep_k<<<(DHID * XPAD + 255) / 256, 256, 0, stream>>>(W1, w1t, W2, w2t, gbk);
  // 2) CSR build: bucket hist -> bucket scan -> direct partition -> fine scatter
  bucket_hist_k<<<(EE + CHUNK - 1) / CHUNK, 512, 0, stream>>>(erow, gbk);
  scan_buckets_k<<<1, 512, 0, stream>>>(gbk, bbase, gcur);
  partition_k<<<(EE + CHUNK - 1) / CHUNK, 256, 0, stream>>>(adj, erow, ecol, gcur, tmp);
  fine_scatter2_k<<<NBK, 512, 0, stream>>>(bbase, tmp, csr, offs, counts);
  // 3) ax = A @ x (gather, bf16 rows, ILP-8, scalar edge loads)
  spmm83_g<<<(NN + 3) / 4, 256, 0, stream>>>(offs, counts, csr, x, ax);
  // 4) z = relu(ax @ W1 + b1) @ W2 via bf16 MFMA (128-node tiles) -> bf16 [NN][32]
  fused_mlp_mfma<<<(NN + 127) / 128, 256, 0, stream>>>(ax, w1t, b1, w2t, zb);
  // 5) out = A @ z + b2 (gather, 1 line per edge, ILP-8)
  spmm25_g<<<(NN + 15) / 16, 256, 0, stream>>>(offs, counts, csr, zb, b2, out);
}

// Round 8
// 442.167 us; speedup vs baseline: 4.0836x; 1.0406x over previous
//
#include <hip/hip_runtime.h>

#define NN   100000
#define EE   3200000
#define DIN  83
#define DHID 1024
#define NCLS 25
#define XPAD 96    // x/ax bf16 row padding (192 B = 3 cache lines)
#define ZPAD 32    // z bf16 row padding (64 B = 1 cache line)

#define NBK     391   // buckets of 256 rows (row >> 8)
#define SLAB    10240 // slab entries per bucket (mean 8192, sigma 90 -> 22 sigma)
#define CHUNK   8192  // edges per partition block

typedef __attribute__((__ext_vector_type__(8))) short sh8;
typedef __attribute__((__ext_vector_type__(4))) float f4_t;

static __device__ __forceinline__ float relu_(float v) { return v > 0.f ? v : 0.f; }

// f32 -> bf16 (RNE)
static __device__ __forceinline__ unsigned short f2bf(float f) {
  unsigned int u = __float_as_uint(f);
  unsigned int r = u + 0x7FFFu + ((u >> 16) & 1u);
  return (unsigned short)(r >> 16);
}
// packed bf16 pair -> two f32
static __device__ __forceinline__ float bflo(unsigned int q) {
  return __uint_as_float(q << 16);
}
static __device__ __forceinline__ float bfhi(unsigned int q) {
  return __uint_as_float(q & 0xFFFF0000u);
}

// K1 (merged prelude): conv1d+sum+relu -> x ; w1t/w2t transposes ; gcur zero.
// One thread per (node, 8-dim group): 12 scalar loads -> 8 outs, 16B store.
__global__ __launch_bounds__(256) void prelude_k(
    const float* __restrict__ feature, const float* __restrict__ conv_w,
    const float* __restrict__ conv_b, unsigned short* __restrict__ x,
    const float* __restrict__ W1, unsigned short* __restrict__ w1t,
    const float* __restrict__ W2, unsigned short* __restrict__ w2t,
    int* __restrict__ gcur) {
  int t = blockIdx.x * 256 + threadIdx.x;
  // --- weight transposes + cursor zero (low index ranges) ---
  if (t < DHID * XPAD) {              // w1t[1024][96] -> [96][1024], K zero-pad
    int k = t / DHID;
    int n = t - k * DHID;
    float v = (k < DIN) ? W1[k * DHID + n] : 0.f;
    w1t[n * XPAD + k] = f2bf(v);
  }
  if (t < 32 * DHID) {                // w2t[32][1024], N zero-padded
    int k = t / 32;
    int n = t - k * 32;
    float v = (n < NCLS) ? W2[k * NCLS + n] : 0.f;
    w2t[n * DHID + k] = f2bf(v);
  }
  if (t < NBK * 16) gcur[t] = 0;
  // --- conv ---
  if (t >= NN * 12) return;
  int n = t / 12;
  int g = t - n * 12;
  int i0 = g * 8;
  float ws0 = conv_w[0] + conv_w[5] + conv_w[10] + conv_w[15];
  float ws1 = conv_w[1] + conv_w[6] + conv_w[11] + conv_w[16];
  float ws2 = conv_w[2] + conv_w[7] + conv_w[12] + conv_w[17];
  float ws3 = conv_w[3] + conv_w[8] + conv_w[13] + conv_w[18];
  float ws4 = conv_w[4] + conv_w[9] + conv_w[14] + conv_w[19];
  float bs  = conv_b[0] + conv_b[1] + conv_b[2] + conv_b[3];
  const float* f = feature + (size_t)n * DIN;
  float fv[12];
#pragma unroll
  for (int k = 0; k < 12; ++k) {
    int idx = i0 - 2 + k;
    fv[k] = (idx >= 0 && idx < DIN) ? f[idx] : 0.f;
  }
  sh8 vout;
#pragma unroll
  for (int j = 0; j < 8; ++j) {
    int i = i0 + j;
    unsigned short o = 0;
    if (i < DIN) {
      float acc = bs + ws0 * fv[j] + ws1 * fv[j + 1] + ws2 * fv[j + 2] +
                  ws3 * fv[j + 3] + ws4 * fv[j + 4];
      o = f2bf(relu_(acc));
    }
    vout[j] = (short)o;
  }
  *(sh8*)&x[(size_t)n * XPAD + i0] = vout;
}

// Pass 1: partition into per-bucket SLABS via direct atomic reservation.
// No histogram/scan prepass needed: slab base = b*SLAB, cursor starts at 0.
__global__ __launch_bounds__(256) void partition_k(
    const float* __restrict__ vals, const int* __restrict__ row,
    const int* __restrict__ col, int* __restrict__ gcur,
    int2* __restrict__ tmp) {
  __shared__ int cnt[NBK];
  __shared__ int lcur[NBK];
  const int tid = threadIdx.x;
  const int cb = blockIdx.x * CHUNK;
  const int csize = (cb + CHUNK <= EE) ? CHUNK : (EE - cb);

  for (int b = tid; b < NBK; b += 256) cnt[b] = 0;
  __syncthreads();
  for (int i = tid; i < csize; i += 256)
    atomicAdd(&cnt[row[cb + i] >> 8], 1);
  __syncthreads();
  for (int b = tid; b < NBK; b += 256)
    lcur[b] = cnt[b] ? (b * SLAB + atomicAdd(&gcur[b * 16], cnt[b])) : 0;
  __syncthreads();
  for (int i = tid; i < csize; i += 256) {
    int r = row[cb + i];
    int pos = atomicAdd(&lcur[r >> 8], 1);
    tmp[pos] = make_int2(col[cb + i] | ((r & 255) << 17),
                         __float_as_int(vals[cb + i]));
  }
}

// Pass 2: per-bucket fine scatter + per-row offset derivation (512 threads).
// Bucket b's edges live in tmp[b*SLAB .. b*SLAB+gcur[b*16]); csr stays
// slab-addressed (offs are absolute indices, downstream is layout-agnostic).
__global__ __launch_bounds__(512) void fine_scatter2_k(
    const int* __restrict__ gcur, const int2* __restrict__ tmp,
    int2* __restrict__ csr, int* __restrict__ offs, int* __restrict__ counts) {
  __shared__ int cnt[256];
  __shared__ int sd[256];
  __shared__ int lcur[256];
  const int tid = threadIdx.x;
  const int b = blockIdx.x;
  const int r0 = b * 256;
  const int gstart = b * SLAB;
  const int nedge = gcur[b * 16];
  if (tid < 256) cnt[tid] = 0;
  __syncthreads();
  // Phase A: per-row histogram (LDS atomics)
  for (int i = tid; i < nedge; i += 512)
    atomicAdd(&cnt[((unsigned)tmp[gstart + i].x) >> 17], 1);
  __syncthreads();
  // Phase B: exclusive scan of 256 row counts (first 256 threads)
  int v = 0;
  if (tid < 256) { v = cnt[tid]; sd[tid] = v; }
  __syncthreads();
  for (int off = 1; off < 256; off <<= 1) {
    int add = (tid >= off && tid < 256) ? sd[tid - off] : 0;
    __syncthreads();
    if (tid < 256) sd[tid] += add;
    __syncthreads();
  }
  if (tid < 256) {
    int excl = gstart + sd[tid] - v;
    int r = r0 + tid;
    if (r < NN) {
      offs[r] = excl;
      counts[r] = v;
    }
    lcur[tid] = excl;
  }
  __syncthreads();
  // Phase C: scatter within the bucket's slab window (L2-local)
  for (int i = tid; i < nedge; i += 512) {
    int2 p = tmp[gstart + i];
    int rl = ((unsigned)p.x) >> 17;
    int pos = atomicAdd(&lcur[rl], 1);
    csr[pos] = make_int2(p.x & 0x1FFFF, p.y);
  }
}

// ---- gather SpMM, D=83(96 bf16): one wave per row, ILP-16, scalar edge loads.
// Declared local roofline on bytes: 343 MB of random 64B-line L2-miss fills
// at ~3.8 TB/s. Byte-reduction variants (LDS atomics / scalar flush / segment
// regs / vector flush) all measured net-negative. ILP 8->16 probes whether
// 3.8 TB/s is a hard fabric wall (csr loads are SGPR-scalarized; regs free).
__global__ __launch_bounds__(256) void spmm83_g(
    const int* __restrict__ offs, const int* __restrict__ cnt,
    const int2* __restrict__ csr, const unsigned short* __restrict__ x,
    unsigned short* __restrict__ ax) {
  int wave = (int)((blockIdx.x * blockDim.x + threadIdx.x) >> 6);
  int lane = threadIdx.x & 63;
  if (wave >= NN) return;
  int s = __builtin_amdgcn_readfirstlane(offs[wave]);   // wave-uniform -> SGPR
  int n = __builtin_amdgcn_readfirstlane(cnt[wave]);
  const bool act = lane < 48;         // 48 lanes x short2 = 96 dims
  const int d2 = lane * 2;
  float a0 = 0.f, a1 = 0.f;
  int i = 0;
  for (; i + 16 <= n; i += 16) {
    int2 p[16];
#pragma unroll
    for (int u = 0; u < 16; ++u) p[u] = csr[s + i + u];
    if (act) {
      unsigned int q[16];
#pragma unroll
      for (int u = 0; u < 16; ++u)
        q[u] = *(const unsigned int*)&x[(size_t)p[u].x * XPAD + d2];
#pragma unroll
      for (int u = 0; u < 16; ++u) {
        float v = __int_as_float(p[u].y);
        a0 += v * bflo(q[u]);
        a1 += v * bfhi(q[u]);
      }
    }
  }
  for (; i + 8 <= n; i += 8) {
    int2 p[8];
#pragma unroll
    for (int u = 0; u < 8; ++u) p[u] = csr[s + i + u];
    if (act) {
      unsigned int q[8];
#pragma unroll
      for (int u = 0; u < 8; ++u)
        q[u] = *(const unsigned int*)&x[(size_t)p[u].x * XPAD + d2];
#pragma unroll
      for (int u = 0; u < 8; ++u) {
        float v = __int_as_float(p[u].y);
        a0 += v * bflo(q[u]);
        a1 += v * bfhi(q[u]);
      }
    }
  }
  for (; i < n; ++i) {
    int2 p = csr[s + i];
    if (act) {
      unsigned int q = *(const unsigned int*)&x[(size_t)p.x * XPAD + d2];
      float v = __int_as_float(p.y);
      a0 += v * bflo(q);
      a1 += v * bfhi(q);
    }
  }
  if (act) {
    unsigned int o = (unsigned int)f2bf(a0) | ((unsigned int)f2bf(a1) << 16);
    *(unsigned int*)&ax[(size_t)wave * XPAD + d2] = o;
  }
}

// ---- gather SpMM, D=25(32 bf16): 4 rows per wave (16 lanes each), ILP-8, +b2 ----
__global__ __launch_bounds__(256) void spmm25_g(
    const int* __restrict__ offs, const int* __restrict__ cnt,
    const int2* __restrict__ csr, const unsigned short* __restrict__ zb,
    const float* __restrict__ b2, float* __restrict__ out) {
  int gw = (int)((blockIdx.x * blockDim.x + threadIdx.x) >> 6);
  int lane = threadIdx.x & 63;
  int sub = lane >> 4;
  int d2 = (lane & 15) * 2;
  int r = gw * 4 + sub;
  if (r >= NN) return;
  int s = offs[r];
  int n = cnt[r];
  float a0 = 0.f, a1 = 0.f;
  int i = 0;
  for (; i + 8 <= n; i += 8) {
    int2 p[8];
#pragma unroll
    for (int u = 0; u < 8; ++u) p[u] = csr[s + i + u];
    unsigned int q[8];
#pragma unroll
    for (int u = 0; u < 8; ++u)
      q[u] = *(const unsigned int*)&zb[(size_t)p[u].x * ZPAD + d2];
#pragma unroll
    for (int u = 0; u < 8; ++u) {
      float v = __int_as_float(p[u].y);
      a0 += v * bflo(q[u]);
      a1 += v * bfhi(q[u]);
    }
  }
  for (; i < n; ++i) {
    int2 p = csr[s + i];
    unsigned int q = *(const unsigned int*)&zb[(size_t)p.x * ZPAD + d2];
    float v = __int_as_float(p.y);
    a0 += v * bflo(q);
    a1 += v * bfhi(q);
  }
  if (d2 < NCLS)     out[(size_t)r * NCLS + d2]     = a0 + b2[d2];
  if (d2 + 1 < NCLS) out[(size_t)r * NCLS + d2 + 1] = a1 + b2[d2 + 1];
}

// ---- Fused MLP via bf16 MFMA: z = relu(ax@W1+b1)@W2, z -> bf16[NN][32] ----
// Block = 128 nodes, 4 waves, hidden chunked x128 (8 chunks).
__global__ __launch_bounds__(256) void fused_mlp_mfma(
    const unsigned short* __restrict__ axg, const unsigned short* __restrict__ w1t,
    const float* __restrict__ b1, const unsigned short* __restrict__ w2t,
    unsigned short* __restrict__ zb) {
  __shared__ __align__(16) unsigned short axs[128 * 104];  // 26.6 KB
  __shared__ __align__(16) unsigned short hs[128 * 136];   // 34.8 KB (chunk 128)
  __shared__ float b1s[DHID];                              // 4 KB
  const int tid = threadIdx.x;
  const int n0 = blockIdx.x * 128;

  for (int idx = tid; idx < 128 * 12; idx += 256) {   // 12 sh8 chunks per row
    int m = idx / 12;
    int c8 = idx - m * 12;
    int node = n0 + m;
    sh8 v = {0, 0, 0, 0, 0, 0, 0, 0};
    if (node < NN) v = *(const sh8*)&axg[(size_t)node * XPAD + c8 * 8];
    *(sh8*)&axs[m * 104 + c8 * 8] = v;
  }
  for (int i = tid; i < DHID; i += 256) b1s[i] = b1[i];
  __syncthreads();

  const int lane = tid & 63;
  const int w = tid >> 6;
  const int quad = lane >> 4;   // A/B frag: k = quad*8 + j
  const int tn = lane & 15;     // A frag: m; B frag: n; C frag: col
  const int mta = w;            // GEMM2 m-tile 1
  const int mtb = w + 4;        // GEMM2 m-tile 2

  sh8 a1[8][3];
#pragma unroll
  for (int mt = 0; mt < 8; ++mt)
#pragma unroll
    for (int kc = 0; kc < 3; ++kc)
      a1[mt][kc] = *(const sh8*)&axs[(mt * 16 + tn) * 104 + kc * 32 + quad * 8];

  f4_t za0 = {0.f, 0.f, 0.f, 0.f}, za1 = {0.f, 0.f, 0.f, 0.f};
  f4_t zb0 = {0.f, 0.f, 0.f, 0.f}, zb1 = {0.f, 0.f, 0.f, 0.f};

  for (int c = 0; c < 8; ++c) {
    const int cb = c * 128;
    // GEMM1: wave w -> n-tiles w*2, w*2+1 ; all 8 m-tiles
#pragma unroll
    for (int nti = 0; nti < 2; ++nti) {
      const int nt = w * 2 + nti;
      const int ng = cb + nt * 16 + tn;
      const unsigned short* wr = &w1t[(size_t)ng * XPAD + quad * 8];
      sh8 b0 = *(const sh8*)&wr[0];
      sh8 b1f = *(const sh8*)&wr[32];
      sh8 b2f = *(const sh8*)&wr[64];
      float bias = b1s[ng];
#pragma unroll
      for (int mt = 0; mt < 8; ++mt) {
        f4_t acc = {0.f, 0.f, 0.f, 0.f};
        acc = __builtin_amdgcn_mfma_f32_16x16x32_bf16(a1[mt][0], b0, acc, 0, 0, 0);
        acc = __builtin_amdgcn_mfma_f32_16x16x32_bf16(a1[mt][1], b1f, acc, 0, 0, 0);
        acc = __builtin_amdgcn_mfma_f32_16x16x32_bf16(a1[mt][2], b2f, acc, 0, 0, 0);
#pragma unroll
        for (int r = 0; r < 4; ++r) {
          float v = relu_(acc[r] + bias);          // C: col=tn, row=quad*4+r
          hs[(mt * 16 + quad * 4 + r) * 136 + nt * 16 + tn] = f2bf(v);
        }
      }
    }
    __syncthreads();
    // GEMM2: z += h_chunk @ W2[cb..cb+127,:]; wave -> m-tiles w, w+4
#pragma unroll
    for (int kc = 0; kc < 4; ++kc) {
      sh8 bl = *(const sh8*)&w2t[(size_t)tn * DHID + cb + kc * 32 + quad * 8];
      sh8 bh = *(const sh8*)&w2t[(size_t)(16 + tn) * DHID + cb + kc * 32 + quad * 8];
      sh8 aa = *(const sh8*)&hs[(mta * 16 + tn) * 136 + kc * 32 + quad * 8];
      za0 = __builtin_amdgcn_mfma_f32_16x16x32_bf16(aa, bl, za0, 0, 0, 0);
      za1 = __builtin_amdgcn_mfma_f32_16x16x32_bf16(aa, bh, za1, 0, 0, 0);
      sh8 ab = *(const sh8*)&hs[(mtb * 16 + tn) * 136 + kc * 32 + quad * 8];
      zb0 = __builtin_amdgcn_mfma_f32_16x16x32_bf16(ab, bl, zb0, 0, 0, 0);
      zb1 = __builtin_amdgcn_mfma_f32_16x16x32_bf16(ab, bh, zb1, 0, 0, 0);
    }
    __syncthreads();
  }

#pragma unroll
  for (int r = 0; r < 4; ++r) {
    int na = n0 + mta * 16 + quad * 4 + r;
    if (na < NN) {
      zb[(size_t)na * ZPAD + tn]      = f2bf(za0[r]);
      zb[(size_t)na * ZPAD + 16 + tn] = f2bf(za1[r]);
    }
    int nb = n0 + mtb * 16 + quad * 4 + r;
    if (nb < NN) {
      zb[(size_t)nb * ZPAD + tn]      = f2bf(zb0[r]);
      zb[(size_t)nb * ZPAD + 16 + tn] = f2bf(zb1[r]);
    }
  }
}

extern "C" void kernel_launch(void* const* d_in, const int* in_sizes, int n_in,
                              void* d_out, int out_size, void* d_ws, size_t ws_size,
                              hipStream_t stream) {
  const float* feature = (const float*)d_in[0];
  const float* conv_w  = (const float*)d_in[1];
  const float* conv_b  = (const float*)d_in[2];
  const float* W1      = (const float*)d_in[3];
  const float* b1      = (const float*)d_in[4];
  const float* W2      = (const float*)d_in[5];
  const float* b2      = (const float*)d_in[6];
  const float* adj     = (const float*)d_in[7];
  const int*   erow    = (const int*)d_in[8];
  const int*   ecol    = (const int*)d_in[9];
  float* out = (float*)d_out;

  char* B = (char*)d_ws;
  size_t o = 0;
  auto alloc = [&](size_t bytes, size_t align) -> void* {
    o = (o + align - 1) & ~(align - 1);
    void* p = B + o;
    o += bytes;
    return p;
  };
  unsigned short* x    = (unsigned short*)alloc((size_t)NN * XPAD * 2, 16);
  unsigned short* ax   = (unsigned short*)alloc((size_t)NN * XPAD * 2, 16);
  unsigned short* zb   = (unsigned short*)alloc((size_t)NN * ZPAD * 2, 16);
  int*   counts  = (int*)alloc((size_t)NN * 4, 16);
  int*   offs    = (int*)alloc((size_t)NN * 4, 16);
  int*   gcur    = (int*)alloc((size_t)NBK * 16 * 4, 64);  // line-padded cursors
  unsigned short* w1t = (unsigned short*)alloc((size_t)DHID * XPAD * 2, 16);
  unsigned short* w2t = (unsigned short*)alloc((size_t)32 * DHID * 2, 16);
  int2*  tmp     = (int2*)alloc((size_t)NBK * SLAB * 8, 16);  // bucket slabs
  int2*  csr     = (int2*)alloc((size_t)NBK * SLAB * 8, 16);  // row-sorted slabs

  // 1) prelude: conv+relu -> x ; weight transposes ; cursor zero (one launch)
  prelude_k<<<(NN * 12 + 255) / 256, 256, 0, stream>>>(
      feature, conv_w, conv_b, x, W1, w1t, W2, w2t, gcur);
  // 2) CSR build: direct slab partition -> fine scatter (2 launches, no scan)
  partition_k<<<(EE + CHUNK - 1) / CHUNK, 256, 0, stream>>>(adj, erow, ecol, gcur, tmp);
  fine_scatter2_k<<<NBK, 512, 0, stream>>>(gcur, tmp, csr, offs, counts);
  // 3) ax = A @ x (gather, bf16 rows, ILP-16, scalar edge loads)
  spmm83_g<<<(NN + 3) / 4, 256, 0, stream>>>(offs, counts, csr, x, ax);
  // 4) z = relu(ax @ W1 + b1) @ W2 via bf16 MFMA (128-node tiles) -> bf16 [NN][32]
  fused_mlp_mfma<<<(NN + 127) / 128, 256, 0, stream>>>(ax, w1t, b1, w2t, zb);
  // 5) out = A @ z + b2 (gather, 1 line per edge, ILP-8)
  spmm25_g<<<(NN + 15) / 16, 256, 0, stream>>>(offs, counts, csr, zb, b2, out);
}